// Round 5
// baseline (177.142 us; speedup 1.0000x reference)
//
#include <hip/hip_runtime.h>
#include <math.h>

#define BB 4
#define NLL 2048
#define CC 128
#define HH 128
#define WW 128
#define NPTS0 32
#define NPTS1 8
#define PP 64
#define FDIM 5
#define FCK (CC*NPTS1 + FDIM)   // 1029
#define FCKP 1032               // padded stride for aligned float4 loads

typedef __attribute__((ext_vector_type(8))) short bf16x8;
typedef __attribute__((ext_vector_type(4))) float f32x4;

__device__ __forceinline__ unsigned short f2bf(float f) {
    union { float f; unsigned u; } v; v.f = f;
    unsigned u = v.u;
    return (unsigned short)((u + 0x7fffu + ((u >> 16) & 1u)) >> 16);
}
__device__ __forceinline__ float bf2f(unsigned short s) {
    union { unsigned u; float f; } v; v.u = ((unsigned)s) << 16;
    return v.f;
}

// ---------------------------------------------------------------------------
// Transpose + fused weight prep (proven round-4 version, unchanged).
// ---------------------------------------------------------------------------
__global__ __launch_bounds__(256)
void transpose_prep(const float* __restrict__ fm, const float* __restrict__ w1,
                    const float* __restrict__ w2, const float* __restrict__ w3,
                    const float* __restrict__ fcw,
                    unsigned short* __restrict__ fmT,
                    unsigned short* __restrict__ W1b,
                    unsigned short* __restrict__ W2b,
                    unsigned short* __restrict__ W3b,
                    float* __restrict__ fcwP) {
    const int t = threadIdx.x;
    if (blockIdx.x >= 512) {
        int gid = (blockIdx.x - 512) * 256 + t;
        for (int e = gid; e < 32800; e += 4096) {
            if (e < 8192) {
                W1b[e] = f2bf(w1[e]);
            } else if (e < 20480) {
                int g = e - 8192;
                int tt = g >> 12, r = g & 4095;
                int p = r >> 6, q = r & 63;
                W2b[tt * 4096 + p * 64 + q] = f2bf(w2[p * 192 + q * 3 + tt]);
            } else if (e < 28672) {
                int g = e - 20480;
                W3b[g] = f2bf(w3[g]);
            } else {
                int g = e - 28672;              // 0..4127
                int o = g / FCKP, r = g - o * FCKP;
                fcwP[g] = (r < FCK) ? fcw[o * FCK + r] : 0.0f;
            }
        }
        return;
    }
    __shared__ unsigned short tile[2][128 * 72];
    const int by = blockIdx.x;            // b*H + y
    const int b = by >> 7, y = by & 127;
    const float* src = fm + ((size_t)b * CC) * (HH * WW) + (size_t)y * WW;
    const int x4 = (t & 31) * 4;          // 0..124
    const int xh = x4 >> 6, xl = x4 & 63;
    #pragma unroll
    for (int i = 0; i < 16; ++i) {
        int r = (t >> 5) + 8 * i;         // channel 0..127
        float4 v = *(const float4*)&src[(size_t)r * (HH * WW) + x4];
        ushort4 u;
        u.x = f2bf(v.x); u.y = f2bf(v.y); u.z = f2bf(v.z); u.w = f2bf(v.w);
        *(ushort4*)&tile[xh][r * 72 + (xl ^ (r & 28))] = u;
    }
    __syncthreads();
    const int c4 = (t & 31) * 4;
    #pragma unroll
    for (int h = 0; h < 2; ++h) {
        unsigned short* dst = fmT + ((size_t)by * WW + h * 64) * CC;
        #pragma unroll
        for (int i = 0; i < 8; ++i) {
            int x = (t >> 5) + 8 * i;     // 0..63
            ushort4 u;
            u.x = tile[h][(c4 + 0) * 72 + (x ^ ((c4 + 0) & 28))];
            u.y = tile[h][(c4 + 1) * 72 + (x ^ ((c4 + 1) & 28))];
            u.z = tile[h][(c4 + 2) * 72 + (x ^ ((c4 + 2) & 28))];
            u.w = tile[h][(c4 + 3) * 72 + (x ^ ((c4 + 3) & 28))];
            *(ushort4*)&dst[(size_t)x * CC + c4] = u;
        }
    }
}

// ---------------------------------------------------------------------------
// Fused line pipeline v5. 4 lines/block (M=32 GEMMs), 256 thr, 4 barriers.
// No P0 phase (coords recomputed per thread), no s_ybn (bn1 applied in-register
// in P2's A-fragment prep), residual s_xs in bf16.
// MFMA 16x16x32 bf16 mapping: A[m=lane&15][k=quad*8+j], C/D col=lane&15,
// row=quad*4+reg.
// ---------------------------------------------------------------------------
__global__ __launch_bounds__(256, 6)
void line_mfma(const unsigned short* __restrict__ fmT,   // (B,H,W,C) bf16
               const float* __restrict__ lines,
               const float* __restrict__ bn1_g, const float* __restrict__ bn1_b,
               const unsigned short* __restrict__ W1b, const float* __restrict__ b1,
               const float* __restrict__ bn2_g, const float* __restrict__ bn2_b,
               const unsigned short* __restrict__ W2b, const float* __restrict__ b2,
               const float* __restrict__ bn3_g, const float* __restrict__ bn3_b,
               const unsigned short* __restrict__ W3b, const float* __restrict__ b3,
               const float* __restrict__ fcwP,  const float* __restrict__ fcb,
               float* __restrict__ out) {
    __shared__ unsigned short s_xs[32 * 136];    // residual, bf16, [m=line*8+k][c]
    __shared__ unsigned short s_z1[4 * 10 * 72]; // conv1 out, rows 0/9 halo zero
    __shared__ unsigned short s_z2[32 * 72];     // conv2 out, [m][q]
    __shared__ float s_red[4 * 8];               // [wave][half*4+o]

    const int bx  = blockIdx.x;
    const int L0  = bx * 4;
    const int b   = bx >> 9;                     // 512 blocks per batch
    const int tid = threadIdx.x;
    const int lane = tid & 63;
    const int wv   = tid >> 6;
    const int quad = lane >> 4;
    const int l16  = lane & 15;
    const float inv_s = 1.0f / sqrtf(1.0f + 1e-5f);

    // ---- P1: bf16 gather + bilinear + maxpool(4) -> s_xs (bf16) ----
    {
        int m = tid >> 3;                 // 0..31 = line*8 + k
        int line = m >> 3, k = m & 7;
        int c16 = (tid & 7) * 16;
        const float* ln = lines + (size_t)(L0 + line) * 4;
        float lx0 = ln[0], ly0 = ln[1], lx1 = ln[2], ly1 = ln[3];
        const unsigned short* base = fmT + (size_t)b * (HH * WW * CC) + c16;
        float acc[16];
        #pragma unroll
        for (int i = 0; i < 16; ++i) acc[i] = -INFINITY;
        #pragma unroll
        for (int j = 0; j < 4; ++j) {
            int pt = k * 4 + j;
            float lam = (float)pt * (1.0f / 31.0f);
            float om  = 1.0f - lam;
            float px = lx0 * lam + lx1 * om - 0.5f;
            float py = ly0 * lam + ly1 * om - 0.5f;
            float px0 = fminf(fmaxf(floorf(px), 0.0f), 127.0f);
            float py0 = fminf(fmaxf(floorf(py), 0.0f), 127.0f);
            float px1 = fminf(px0 + 1.0f, 127.0f);
            float py1 = fminf(py0 + 1.0f, 127.0f);
            int ix0 = (int)px0, ix1 = (int)px1, iy0 = (int)py0, iy1 = (int)py1;
            float ax = px1 - px, bxv = px - px0, ay = py1 - py, byv = py - py0;
            // exact reference pairing (its bilinear weights are x/y-swapped)
            float wA = ax * ay, wB = bxv * ay, wC = ax * byv, wD = bxv * byv;
            int oA = (iy0 * WW + ix0) * CC, oB = (iy1 * WW + ix0) * CC;
            int oC = (iy0 * WW + ix1) * CC, oD = (iy1 * WW + ix1) * CC;
            bf16x8 a0 = *(const bf16x8*)(base + oA);
            bf16x8 a1 = *(const bf16x8*)(base + oA + 8);
            bf16x8 b0 = *(const bf16x8*)(base + oB);
            bf16x8 b1v = *(const bf16x8*)(base + oB + 8);
            bf16x8 c0 = *(const bf16x8*)(base + oC);
            bf16x8 c1 = *(const bf16x8*)(base + oC + 8);
            bf16x8 d0 = *(const bf16x8*)(base + oD);
            bf16x8 d1 = *(const bf16x8*)(base + oD + 8);
            #pragma unroll
            for (int i = 0; i < 8; ++i) {
                float v = wA * bf2f((unsigned short)a0[i])
                        + wB * bf2f((unsigned short)b0[i])
                        + wC * bf2f((unsigned short)c0[i])
                        + wD * bf2f((unsigned short)d0[i]);
                acc[i] = fmaxf(acc[i], v);
                float v2 = wA * bf2f((unsigned short)a1[i])
                         + wB * bf2f((unsigned short)b1v[i])
                         + wC * bf2f((unsigned short)c1[i])
                         + wD * bf2f((unsigned short)d1[i]);
                acc[8 + i] = fmaxf(acc[8 + i], v2);
            }
        }
        bf16x8 lo, hi;
        #pragma unroll
        for (int i = 0; i < 8; ++i) {
            lo[i] = (short)f2bf(acc[i]);
            hi[i] = (short)f2bf(acc[8 + i]);
        }
        *(bf16x8*)&s_xs[m * 136 + c16]     = lo;
        *(bf16x8*)&s_xs[m * 136 + c16 + 8] = hi;
    }
    __syncthreads();

    // ---- P2: conv1 (M=32,K=128,N=64), bn1 applied in-register -> s_z1 ----
    {
        int mh = wv & 1, nh = wv >> 1;
        int mrow = mh * 16 + l16;
        bf16x8 afr[4];
        #pragma unroll
        for (int kc = 0; kc < 4; ++kc) {
            bf16x8 x = *(const bf16x8*)&s_xs[mrow * 136 + kc * 32 + quad * 8];
            int c0 = kc * 32 + quad * 8;
            float4 g0 = *(const float4*)(bn1_g + c0);
            float4 g1 = *(const float4*)(bn1_g + c0 + 4);
            float4 bb0 = *(const float4*)(bn1_b + c0);
            float4 bb1 = *(const float4*)(bn1_b + c0 + 4);
            float gs[8] = {g0.x, g0.y, g0.z, g0.w, g1.x, g1.y, g1.z, g1.w};
            float bs[8] = {bb0.x, bb0.y, bb0.z, bb0.w, bb1.x, bb1.y, bb1.z, bb1.w};
            bf16x8 pk;
            #pragma unroll
            for (int i = 0; i < 8; ++i) {
                float v = fmaxf(bf2f((unsigned short)x[i]) * (gs[i] * inv_s) + bs[i], 0.0f);
                pk[i] = (short)f2bf(v);
            }
            afr[kc] = pk;
        }
        #pragma unroll
        for (int sub = 0; sub < 2; ++sub) {
            int p = nh * 32 + sub * 16 + l16;
            f32x4 acc = {0.f, 0.f, 0.f, 0.f};
            #pragma unroll
            for (int kc = 0; kc < 4; ++kc) {
                bf16x8 bf = *(const bf16x8*)(W1b + p * 128 + kc * 32 + quad * 8);
                acc = __builtin_amdgcn_mfma_f32_16x16x32_bf16(afr[kc], bf, acc, 0, 0, 0);
            }
            float s2 = bn2_g[p] * inv_s, bb2 = bn2_b[p], cb = b1[p];
            #pragma unroll
            for (int r = 0; r < 4; ++r) {
                int mm = mh * 16 + quad * 4 + r;
                int lline = mm >> 3, kk = mm & 7;
                float v = fmaxf((acc[r] + cb) * s2 + bb2, 0.0f);
                s_z1[lline * 720 + (kk + 1) * 72 + p] = f2bf(v);
            }
        }
        // halo rows 0/9 of each line's z1 tile
        #pragma unroll
        for (int e = tid; e < 512; e += 256) {
            int lline = e >> 7;
            int rr = (e >> 6) & 1;
            int q = e & 63;
            s_z1[lline * 720 + (rr ? 9 : 0) * 72 + q] = 0;
        }
    }
    __syncthreads();

    // ---- P3: conv2 (3 shifted GEMMs, M=32,K=64,N=64) + bn3 + relu -> s_z2 ----
    {
        int mh = wv & 1, nh = wv >> 1;
        int mrow = mh * 16 + l16;
        int linea = mrow >> 3, ka = mrow & 7;
        const unsigned short* arow = s_z1 + linea * 720 + ka * 72;
        bf16x8 afr[3][2];
        #pragma unroll
        for (int t = 0; t < 3; ++t)
            #pragma unroll
            for (int kc = 0; kc < 2; ++kc)
                afr[t][kc] = *(const bf16x8*)&arow[t * 72 + kc * 32 + quad * 8];
        #pragma unroll
        for (int sub = 0; sub < 2; ++sub) {
            int p = nh * 32 + sub * 16 + l16;
            f32x4 acc = {0.f, 0.f, 0.f, 0.f};
            #pragma unroll
            for (int t = 0; t < 3; ++t) {
                #pragma unroll
                for (int kc = 0; kc < 2; ++kc) {
                    bf16x8 bf = *(const bf16x8*)(W2b + t * 4096 + p * 64 + kc * 32 + quad * 8);
                    acc = __builtin_amdgcn_mfma_f32_16x16x32_bf16(afr[t][kc], bf, acc, 0, 0, 0);
                }
            }
            float s3 = bn3_g[p] * inv_s, bb3 = bn3_b[p], cb = b2[p];
            #pragma unroll
            for (int r = 0; r < 4; ++r) {
                int mm = mh * 16 + quad * 4 + r;
                float v = fmaxf((acc[r] + cb) * s3 + bb3, 0.0f);
                s_z2[mm * 72 + p] = f2bf(v);
            }
        }
    }
    __syncthreads();

    // ---- P4: conv3 (M=32,K=64,N=128) + residual + relu + fc2 partials ----
    float p0 = 0.f, p1 = 0.f, p2 = 0.f, p3 = 0.f;
    {
        int mh = wv & 1;
        int n0 = (wv >> 1) * 64;
        int mrow = mh * 16 + l16;
        bf16x8 a0 = *(const bf16x8*)&s_z2[mrow * 72 + quad * 8];
        bf16x8 a1 = *(const bf16x8*)&s_z2[mrow * 72 + 32 + quad * 8];
        int kbase = (quad & 1) * 4;
        #pragma unroll
        for (int sub = 0; sub < 4; ++sub) {
            int c = n0 + sub * 16 + l16;
            f32x4 acc = {0.f, 0.f, 0.f, 0.f};
            bf16x8 bf0 = *(const bf16x8*)(W3b + c * 64 + quad * 8);
            bf16x8 bf1 = *(const bf16x8*)(W3b + c * 64 + 32 + quad * 8);
            acc = __builtin_amdgcn_mfma_f32_16x16x32_bf16(a0, bf0, acc, 0, 0, 0);
            acc = __builtin_amdgcn_mfma_f32_16x16x32_bf16(a1, bf1, acc, 0, 0, 0);
            float cb = b3[c];
            int idx = c * 8 + kbase;
            float4 w0 = *(const float4*)(fcwP + 0 * FCKP + idx);
            float4 w1v = *(const float4*)(fcwP + 1 * FCKP + idx);
            float4 w2v = *(const float4*)(fcwP + 2 * FCKP + idx);
            float4 w3v = *(const float4*)(fcwP + 3 * FCKP + idx);
            const float* w0a = (const float*)&w0;
            const float* w1a = (const float*)&w1v;
            const float* w2a = (const float*)&w2v;
            const float* w3a = (const float*)&w3v;
            #pragma unroll
            for (int r = 0; r < 4; ++r) {
                int mm = mh * 16 + quad * 4 + r;
                float xv = bf2f(s_xs[mm * 136 + c]);
                float v = fmaxf(xv + acc[r] + cb, 0.0f);
                p0 = fmaf(v, w0a[r], p0);
                p1 = fmaf(v, w1a[r], p1);
                p2 = fmaf(v, w2a[r], p2);
                p3 = fmaf(v, w3a[r], p3);
            }
        }
    }
    // reduce within 32-lane halves (each half = one line of this wave's m-half)
    #pragma unroll
    for (int off = 16; off >= 1; off >>= 1) {
        p0 += __shfl_down(p0, off);
        p1 += __shfl_down(p1, off);
        p2 += __shfl_down(p2, off);
        p3 += __shfl_down(p3, off);
    }
    if ((lane & 31) == 0) {
        int h = lane >> 5;
        s_red[wv * 8 + h * 4 + 0] = p0;
        s_red[wv * 8 + h * 4 + 1] = p1;
        s_red[wv * 8 + h * 4 + 2] = p2;
        s_red[wv * 8 + h * 4 + 3] = p3;
    }
    __syncthreads();

    // ---- P5: finish logits + softmax (one thread per line) ----
    if (tid < 4) {
        int line = tid;
        int wa = line >> 1;              // wave with matching m-half, n-half 0
        int h  = (line & 1) * 4;
        float lg[4];
        #pragma unroll
        for (int o = 0; o < 4; ++o)
            lg[o] = fcb[o] + s_red[wa * 8 + h + o] + s_red[(wa + 2) * 8 + h + o];
        const float* ln = lines + (size_t)(L0 + line) * 4;
        float ux = ln[0], uy = ln[1], vx = ln[2], vy = ln[3];
        float dx = ux - vx, dy = uy - vy;
        float d = fmaxf(sqrtf(dx * dx + dy * dy), 1e-6f);
        float ft[FDIM] = {ux * (1.0f / 128.0f), uy * (1.0f / 128.0f),
                          vx * (1.0f / 128.0f), vy * (1.0f / 128.0f), d};
        #pragma unroll
        for (int j = 0; j < FDIM; ++j) {
            float fv = fmaxf(ft[j], 0.0f);
            #pragma unroll
            for (int o = 0; o < 4; ++o)
                lg[o] = fmaf(fv, fcwP[o * FCKP + 1024 + j], lg[o]);
        }
        float m = fmaxf(fmaxf(lg[0], lg[1]), fmaxf(lg[2], lg[3]));
        float e0 = expf(lg[0] - m), e1 = expf(lg[1] - m);
        float e2 = expf(lg[2] - m), e3 = expf(lg[3] - m);
        float inv = 1.0f / (e0 + e1 + e2 + e3);
        float* lo = out + (size_t)(L0 + line) * 4;
        lo[0] = lg[0]; lo[1] = lg[1]; lo[2] = lg[2]; lo[3] = lg[3];
        float* pr = out + (size_t)BB * NLL * 4 + (size_t)(L0 + line) * 4;
        pr[0] = e0 * inv; pr[1] = e1 * inv; pr[2] = e2 * inv; pr[3] = e3 * inv;
    }
}

// ---------------------------------------------------------------------------
// Fallbacks (small-ws paths): round-1 proven VALU kernel + fp32 transpose.
// ---------------------------------------------------------------------------
__global__ __launch_bounds__(256)
void transpose_fm2(const float* __restrict__ fm, float* __restrict__ fmT) {
    __shared__ float tile[32 * 132];
    const int c0 = blockIdx.x * 32;
    const int by = blockIdx.y;
    const int b = by >> 7, y = by & 127;
    const int t = threadIdx.x;
    const float* src = fm + ((size_t)b * CC) * (HH * WW) + (size_t)y * WW;
    const int x4 = (t & 31) * 4;
    #pragma unroll
    for (int i = 0; i < 4; ++i) {
        int r = (t >> 5) + 8 * i;
        *(float4*)&tile[r * 132 + x4] =
            *(const float4*)&src[(size_t)(c0 + r) * (HH * WW) + x4];
    }
    __syncthreads();
    float* dst = fmT + (size_t)by * WW * CC + c0 + (t & 31);
    const int cr = (t & 31) * 132;
    #pragma unroll
    for (int i = 0; i < 16; ++i) {
        int x = (t >> 5) + 8 * i;
        dst[(size_t)x * CC] = tile[cr + x];
    }
}

template<bool TRANS>
__global__ __launch_bounds__(256)
void line_kernel_v1(const float* __restrict__ fm,
                    const float* __restrict__ lines,
                    const float* __restrict__ bn1_g, const float* __restrict__ bn1_b,
                    const float* __restrict__ w1,    const float* __restrict__ b1,
                    const float* __restrict__ bn2_g, const float* __restrict__ bn2_b,
                    const float* __restrict__ w2,    const float* __restrict__ b2,
                    const float* __restrict__ bn3_g, const float* __restrict__ bn3_b,
                    const float* __restrict__ w3,    const float* __restrict__ b3,
                    const float* __restrict__ fcw,   const float* __restrict__ fcb,
                    float* __restrict__ out) {
    __shared__ int   s_ix0[32], s_ix1[32], s_iy0[32], s_iy1[32];
    __shared__ float s_wA[32], s_wB[32], s_wC[32], s_wD[32];
    __shared__ float xs [8][132];
    __shared__ float ybn[8][132];
    __shared__ float z1 [64][12];
    __shared__ float z2 [64][8];
    __shared__ float s_feat[8];
    __shared__ float s_red[16];

    const int L   = blockIdx.x;
    const int b   = L / NLL;
    const int tid = threadIdx.x;
    const float inv_s = 1.0f / sqrtf(1.0f + 1e-5f);
    const float* ln = lines + (size_t)L * 4;

    if (tid < 32) {
        float lam = (float)tid * (1.0f / 31.0f);
        float om  = 1.0f - lam;
        float px = ln[0] * lam + ln[2] * om - 0.5f;
        float py = ln[1] * lam + ln[3] * om - 0.5f;
        float px0 = fminf(fmaxf(floorf(px), 0.0f), 127.0f);
        float py0 = fminf(fmaxf(floorf(py), 0.0f), 127.0f);
        float px1 = fminf(px0 + 1.0f, 127.0f);
        float py1 = fminf(py0 + 1.0f, 127.0f);
        s_ix0[tid] = (int)px0; s_ix1[tid] = (int)px1;
        s_iy0[tid] = (int)py0; s_iy1[tid] = (int)py1;
        float ax = px1 - px, bxv = px - px0, ay = py1 - py, byv = py - py0;
        s_wA[tid] = ax  * ay;  s_wB[tid] = bxv * ay;
        s_wC[tid] = ax  * byv; s_wD[tid] = bxv * byv;
    }
    if (tid == 0) {
        float ux = ln[0], uy = ln[1], vx = ln[2], vy = ln[3];
        float dx = ux - vx, dy = uy - vy;
        float d = fmaxf(sqrtf(dx * dx + dy * dy), 1e-6f);
        s_feat[0] = ux / 128.0f; s_feat[1] = uy / 128.0f;
        s_feat[2] = vx / 128.0f; s_feat[3] = vy / 128.0f;
        s_feat[4] = d;
    }
    __syncthreads();
    {
        int cq = tid & 31, k = tid >> 5, c0 = cq * 4;
        float4 acc;
        acc.x = -INFINITY; acc.y = -INFINITY; acc.z = -INFINITY; acc.w = -INFINITY;
        #pragma unroll
        for (int j = 0; j < 4; ++j) {
            int pt = k * 4 + j;
            int ix0 = s_ix0[pt], ix1 = s_ix1[pt];
            int iy0 = s_iy0[pt], iy1 = s_iy1[pt];
            float wA = s_wA[pt], wB = s_wB[pt], wC = s_wC[pt], wD = s_wD[pt];
            float4 vA, vB, vC, vD;
            if (TRANS) {
                const float* base = fm + (size_t)b * HH * WW * CC;
                vA = *(const float4*)(base + ((size_t)(iy0 * WW + ix0)) * CC + c0);
                vB = *(const float4*)(base + ((size_t)(iy1 * WW + ix0)) * CC + c0);
                vC = *(const float4*)(base + ((size_t)(iy0 * WW + ix1)) * CC + c0);
                vD = *(const float4*)(base + ((size_t)(iy1 * WW + ix1)) * CC + c0);
            } else {
                const float* base = fm + ((size_t)b * CC + c0) * HH * WW;
                int oA = iy0 * WW + ix0, oB = iy1 * WW + ix0;
                int oC = iy0 * WW + ix1, oD = iy1 * WW + ix1;
                vA.x = base[oA];           vB.x = base[oB];
                vC.x = base[oC];           vD.x = base[oD];
                vA.y = base[HH*WW + oA];   vB.y = base[HH*WW + oB];
                vC.y = base[HH*WW + oC];   vD.y = base[HH*WW + oD];
                vA.z = base[2*HH*WW + oA]; vB.z = base[2*HH*WW + oB];
                vC.z = base[2*HH*WW + oC]; vD.z = base[2*HH*WW + oD];
                vA.w = base[3*HH*WW + oA]; vB.w = base[3*HH*WW + oB];
                vC.w = base[3*HH*WW + oC]; vD.w = base[3*HH*WW + oD];
            }
            float4 v;
            v.x = wA * vA.x + wB * vB.x + wC * vC.x + wD * vD.x;
            v.y = wA * vA.y + wB * vB.y + wC * vC.y + wD * vD.y;
            v.z = wA * vA.z + wB * vB.z + wC * vC.z + wD * vD.z;
            v.w = wA * vA.w + wB * vB.w + wC * vC.w + wD * vD.w;
            acc.x = fmaxf(acc.x, v.x); acc.y = fmaxf(acc.y, v.y);
            acc.z = fmaxf(acc.z, v.z); acc.w = fmaxf(acc.w, v.w);
        }
        *(float4*)(&xs[k][c0]) = acc;
    }
    __syncthreads();
    for (int e = tid; e < 1024; e += 256) {
        int k = e >> 7, c = e & 127;
        ybn[k][c] = fmaxf(xs[k][c] * (bn1_g[c] * inv_s) + bn1_b[c], 0.0f);
    }
    __syncthreads();
    if (tid < 64) { z1[tid][0] = 0.0f; z1[tid][9] = 0.0f; }
    {
        int p = tid >> 2, kq = tid & 3;
        const float* wrow = w1 + p * 128;
        float a0a = 0.f, a0b = 0.f, a1a = 0.f, a1b = 0.f;
        #pragma unroll 8
        for (int c = 0; c < 128; c += 4) {
            float4 w  = *(const float4*)(wrow + c);
            float4 ya = *(const float4*)(&ybn[kq][c]);
            float4 yb = *(const float4*)(&ybn[kq + 4][c]);
            a0a = fmaf(w.x, ya.x, a0a); a0b = fmaf(w.y, ya.y, a0b);
            a0a = fmaf(w.z, ya.z, a0a); a0b = fmaf(w.w, ya.w, a0b);
            a1a = fmaf(w.x, yb.x, a1a); a1b = fmaf(w.y, yb.y, a1b);
            a1a = fmaf(w.z, yb.z, a1a); a1b = fmaf(w.w, yb.w, a1b);
        }
        float s2 = bn2_g[p] * inv_s, bb = bn2_b[p], cb = b1[p];
        z1[p][1 + kq]     = fmaxf((a0a + a0b + cb) * s2 + bb, 0.0f);
        z1[p][1 + kq + 4] = fmaxf((a1a + a1b + cb) * s2 + bb, 0.0f);
    }
    __syncthreads();
    {
        int p = tid >> 2, kq = tid & 3;
        const float* wrow = w2 + p * 192;
        float acc0 = 0.f, acc1 = 0.f;
        #pragma unroll 4
        for (int q = 0; q < 64; ++q) {
            float w0 = wrow[q * 3 + 0], w1v = wrow[q * 3 + 1], w2v = wrow[q * 3 + 2];
            const float* zr = &z1[q][0];
            acc0 = fmaf(w0, zr[kq], acc0);
            acc0 = fmaf(w1v, zr[kq + 1], acc0);
            acc0 = fmaf(w2v, zr[kq + 2], acc0);
            acc1 = fmaf(w0, zr[kq + 4], acc1);
            acc1 = fmaf(w1v, zr[kq + 5], acc1);
            acc1 = fmaf(w2v, zr[kq + 6], acc1);
        }
        float s3 = bn3_g[p] * inv_s, bb = bn3_b[p], cb = b2[p];
        z2[p][kq]     = fmaxf((acc0 + cb) * s3 + bb, 0.0f);
        z2[p][kq + 4] = fmaxf((acc1 + cb) * s3 + bb, 0.0f);
    }
    __syncthreads();
    float part0 = 0.f, part1 = 0.f, part2 = 0.f, part3 = 0.f;
    {
        int c = tid >> 1, kq = tid & 1;
        const float* wrow = w3 + c * 64;
        float acc[4] = {0.f, 0.f, 0.f, 0.f};
        #pragma unroll 8
        for (int q = 0; q < 64; ++q) {
            float w = wrow[q];
            acc[0] = fmaf(w, z2[q][kq], acc[0]);
            acc[1] = fmaf(w, z2[q][kq + 2], acc[1]);
            acc[2] = fmaf(w, z2[q][kq + 4], acc[2]);
            acc[3] = fmaf(w, z2[q][kq + 6], acc[3]);
        }
        float cb = b3[c];
        #pragma unroll
        for (int i = 0; i < 4; ++i) {
            int k = kq + 2 * i;
            float v = fmaxf(xs[k][c] + acc[i] + cb, 0.0f);
            int idx = c * 8 + k;
            part0 = fmaf(v, fcw[0 * FCK + idx], part0);
            part1 = fmaf(v, fcw[1 * FCK + idx], part1);
            part2 = fmaf(v, fcw[2 * FCK + idx], part2);
            part3 = fmaf(v, fcw[3 * FCK + idx], part3);
        }
    }
    #pragma unroll
    for (int off = 32; off > 0; off >>= 1) {
        part0 += __shfl_down(part0, off);
        part1 += __shfl_down(part1, off);
        part2 += __shfl_down(part2, off);
        part3 += __shfl_down(part3, off);
    }
    if ((tid & 63) == 0) {
        int w = tid >> 6;
        s_red[w * 4 + 0] = part0; s_red[w * 4 + 1] = part1;
        s_red[w * 4 + 2] = part2; s_red[w * 4 + 3] = part3;
    }
    __syncthreads();
    if (tid == 0) {
        float lg[4];
        #pragma unroll
        for (int o = 0; o < 4; ++o)
            lg[o] = fcb[o] + s_red[o] + s_red[4 + o] + s_red[8 + o] + s_red[12 + o];
        #pragma unroll
        for (int j = 0; j < FDIM; ++j) {
            float fv = fmaxf(s_feat[j], 0.0f);
            #pragma unroll
            for (int o = 0; o < 4; ++o)
                lg[o] = fmaf(fv, fcw[o * FCK + 1024 + j], lg[o]);
        }
        float m = fmaxf(fmaxf(lg[0], lg[1]), fmaxf(lg[2], lg[3]));
        float e0 = expf(lg[0] - m), e1 = expf(lg[1] - m);
        float e2 = expf(lg[2] - m), e3 = expf(lg[3] - m);
        float inv = 1.0f / (e0 + e1 + e2 + e3);
        float* lo = out + (size_t)L * 4;
        lo[0] = lg[0]; lo[1] = lg[1]; lo[2] = lg[2]; lo[3] = lg[3];
        float* pr = out + (size_t)BB * NLL * 4 + (size_t)L * 4;
        pr[0] = e0 * inv; pr[1] = e1 * inv; pr[2] = e2 * inv; pr[3] = e3 * inv;
    }
}

extern "C" void kernel_launch(void* const* d_in, const int* in_sizes, int n_in,
                              void* d_out, int out_size, void* d_ws, size_t ws_size,
                              hipStream_t stream) {
    const float* fm     = (const float*)d_in[0];
    const float* lines  = (const float*)d_in[1];
    const float* bn1_g  = (const float*)d_in[2];
    const float* bn1_b  = (const float*)d_in[3];
    const float* w1     = (const float*)d_in[4];
    const float* b1     = (const float*)d_in[5];
    const float* bn2_g  = (const float*)d_in[6];
    const float* bn2_b  = (const float*)d_in[7];
    const float* w2     = (const float*)d_in[8];
    const float* b2     = (const float*)d_in[9];
    const float* bn3_g  = (const float*)d_in[10];
    const float* bn3_b  = (const float*)d_in[11];
    const float* w3     = (const float*)d_in[12];
    const float* b3     = (const float*)d_in[13];
    const float* fcw    = (const float*)d_in[14];
    const float* fcb    = (const float*)d_in[15];
    float* out = (float*)d_out;

    const size_t fmTb_bytes = (size_t)BB * HH * WW * CC * sizeof(unsigned short); // 8 MiB
    const size_t fmTf_bytes = (size_t)BB * HH * WW * CC * sizeof(float);          // 32 MiB
    const size_t wb_bytes   = 57344;                    // W1b+W2b+W3b (bf16)
    const size_t fcwP_bytes = 4 * FCKP * sizeof(float); // 16512

    if (ws_size >= fmTb_bytes + wb_bytes + fcwP_bytes) {
        unsigned short* fmT = (unsigned short*)d_ws;
        unsigned short* W1b = (unsigned short*)((char*)d_ws + fmTb_bytes);
        unsigned short* W2b = W1b + 8192;
        unsigned short* W3b = W2b + 12288;
        float* fcwP = (float*)((char*)d_ws + fmTb_bytes + wb_bytes);
        transpose_prep<<<512 + 16, 256, 0, stream>>>(
            fm, w1, w2, w3, fcw, fmT, W1b, W2b, W3b, fcwP);
        line_mfma<<<BB * NLL / 4, 256, 0, stream>>>(
            fmT, lines, bn1_g, bn1_b, W1b, b1, bn2_g, bn2_b, W2b, b2,
            bn3_g, bn3_b, W3b, b3, fcwP, fcb, out);
    } else if (ws_size >= fmTf_bytes) {
        float* fmT = (float*)d_ws;
        dim3 tg(CC / 32, BB * HH);
        transpose_fm2<<<tg, 256, 0, stream>>>(fm, fmT);
        line_kernel_v1<true><<<BB * NLL, 256, 0, stream>>>(
            fmT, lines, bn1_g, bn1_b, w1, b1, bn2_g, bn2_b, w2, b2,
            bn3_g, bn3_b, w3, b3, fcw, fcb, out);
    } else {
        line_kernel_v1<false><<<BB * NLL, 256, 0, stream>>>(
            fm, lines, bn1_g, bn1_b, w1, b1, bn2_g, bn2_b, w2, b2,
            bn3_g, bn3_b, w3, b3, fcw, fcb, out);
    }
}

// Round 6
// 163.614 us; speedup vs baseline: 1.0827x; 1.0827x over previous
//
#include <hip/hip_runtime.h>
#include <math.h>

#define BB 4
#define NLL 2048
#define CC 128
#define HH 128
#define WW 128
#define NPTS0 32
#define NPTS1 8
#define PP 64
#define FDIM 5
#define FCK (CC*NPTS1 + FDIM)   // 1029
#define FCKP 1032               // padded stride for aligned float4 loads

typedef __attribute__((ext_vector_type(8))) short bf16x8;
typedef __attribute__((ext_vector_type(4))) float f32x4;

__device__ __forceinline__ unsigned short f2bf(float f) {
    union { float f; unsigned u; } v; v.f = f;
    unsigned u = v.u;
    return (unsigned short)((u + 0x7fffu + ((u >> 16) & 1u)) >> 16);
}
__device__ __forceinline__ float bf2f(unsigned short s) {
    union { unsigned u; float f; } v; v.u = ((unsigned)s) << 16;
    return v.f;
}

// ---------------------------------------------------------------------------
// Transpose + fused weight prep (proven round-4 version, unchanged).
// ---------------------------------------------------------------------------
__global__ __launch_bounds__(256)
void transpose_prep(const float* __restrict__ fm, const float* __restrict__ w1,
                    const float* __restrict__ w2, const float* __restrict__ w3,
                    const float* __restrict__ fcw,
                    unsigned short* __restrict__ fmT,
                    unsigned short* __restrict__ W1b,
                    unsigned short* __restrict__ W2b,
                    unsigned short* __restrict__ W3b,
                    float* __restrict__ fcwP) {
    const int t = threadIdx.x;
    if (blockIdx.x >= 512) {
        int gid = (blockIdx.x - 512) * 256 + t;
        for (int e = gid; e < 32800; e += 4096) {
            if (e < 8192) {
                W1b[e] = f2bf(w1[e]);
            } else if (e < 20480) {
                int g = e - 8192;
                int tt = g >> 12, r = g & 4095;
                int p = r >> 6, q = r & 63;
                W2b[tt * 4096 + p * 64 + q] = f2bf(w2[p * 192 + q * 3 + tt]);
            } else if (e < 28672) {
                int g = e - 20480;
                W3b[g] = f2bf(w3[g]);
            } else {
                int g = e - 28672;              // 0..4127
                int o = g / FCKP, r = g - o * FCKP;
                fcwP[g] = (r < FCK) ? fcw[o * FCK + r] : 0.0f;
            }
        }
        return;
    }
    __shared__ unsigned short tile[2][128 * 72];
    const int by = blockIdx.x;            // b*H + y
    const int b = by >> 7, y = by & 127;
    const float* src = fm + ((size_t)b * CC) * (HH * WW) + (size_t)y * WW;
    const int x4 = (t & 31) * 4;          // 0..124
    const int xh = x4 >> 6, xl = x4 & 63;
    #pragma unroll
    for (int i = 0; i < 16; ++i) {
        int r = (t >> 5) + 8 * i;         // channel 0..127
        float4 v = *(const float4*)&src[(size_t)r * (HH * WW) + x4];
        ushort4 u;
        u.x = f2bf(v.x); u.y = f2bf(v.y); u.z = f2bf(v.z); u.w = f2bf(v.w);
        *(ushort4*)&tile[xh][r * 72 + (xl ^ (r & 28))] = u;
    }
    __syncthreads();
    const int c4 = (t & 31) * 4;
    #pragma unroll
    for (int h = 0; h < 2; ++h) {
        unsigned short* dst = fmT + ((size_t)by * WW + h * 64) * CC;
        #pragma unroll
        for (int i = 0; i < 8; ++i) {
            int x = (t >> 5) + 8 * i;     // 0..63
            ushort4 u;
            u.x = tile[h][(c4 + 0) * 72 + (x ^ ((c4 + 0) & 28))];
            u.y = tile[h][(c4 + 1) * 72 + (x ^ ((c4 + 1) & 28))];
            u.z = tile[h][(c4 + 2) * 72 + (x ^ ((c4 + 2) & 28))];
            u.w = tile[h][(c4 + 3) * 72 + (x ^ ((c4 + 3) & 28))];
            *(ushort4*)&dst[(size_t)x * CC + c4] = u;
        }
    }
}

// ---------------------------------------------------------------------------
// Fused line pipeline v6. 4 lines/block (M=32 GEMMs), 256 thr, 5 barriers.
// P1 register footprint = round-4's proven no-spill shape (acc[8], 4 loads),
// looped over two m-halves. Coord/weight LDS arrays aliased with s_z1
// (dead after P1 / live after P2's barrier).
// MFMA 16x16x32 bf16 mapping: A[m=lane&15][k=quad*8+j], C/D col=lane&15,
// row=quad*4+reg.
// ---------------------------------------------------------------------------
__global__ __launch_bounds__(256, 8)
void line_mfma(const unsigned short* __restrict__ fmT,   // (B,H,W,C) bf16
               const float* __restrict__ lines,
               const float* __restrict__ bn1_g, const float* __restrict__ bn1_b,
               const unsigned short* __restrict__ W1b, const float* __restrict__ b1,
               const float* __restrict__ bn2_g, const float* __restrict__ bn2_b,
               const unsigned short* __restrict__ W2b, const float* __restrict__ b2,
               const float* __restrict__ bn3_g, const float* __restrict__ bn3_b,
               const unsigned short* __restrict__ W3b, const float* __restrict__ b3,
               const float* __restrict__ fcwP,  const float* __restrict__ fcb,
               float* __restrict__ out) {
    // LDS layout (19200 B total):
    //   [0,5760):     s_z1 (conv1 out, 4*10*72 bf16) -- ALIASED with
    //                 s_oA/B/C/D[128] + s_wA/B/C/D[128] (4 KB, P0/P1 only)
    //   [5760,14464): s_xs (residual bf16, [m=line*8+k][c], stride 136)
    //   [14464,19072): s_z2 (conv2 out, [m][q], stride 72)
    //   [19072,19200): s_red
    __shared__ __align__(16) char smem[19200];
    int*   s_oA = (int*)(smem + 0);
    int*   s_oB = (int*)(smem + 512);
    int*   s_oC = (int*)(smem + 1024);
    int*   s_oD = (int*)(smem + 1536);
    float* s_wA = (float*)(smem + 2048);
    float* s_wB = (float*)(smem + 2560);
    float* s_wC = (float*)(smem + 3072);
    float* s_wD = (float*)(smem + 3584);
    unsigned short* s_z1 = (unsigned short*)(smem + 0);
    unsigned short* s_xs = (unsigned short*)(smem + 5760);
    unsigned short* s_z2 = (unsigned short*)(smem + 14464);
    float* s_red = (float*)(smem + 19072);

    const int bx  = blockIdx.x;
    const int L0  = bx * 4;
    const int b   = bx >> 9;                     // 512 blocks per batch
    const int tid = threadIdx.x;
    const int lane = tid & 63;
    const int wv   = tid >> 6;
    const int quad = lane >> 4;
    const int l16  = lane & 15;
    const float inv_s = 1.0f / sqrtf(1.0f + 1e-5f);

    // ---- P0: per-point offsets/weights for 4 lines (128 points) ----
    if (tid < 128) {
        int line = tid >> 5, pt = tid & 31;
        const float* ln = lines + (size_t)(L0 + line) * 4;
        float lam = (float)pt * (1.0f / 31.0f);
        float om  = 1.0f - lam;
        float px = ln[0] * lam + ln[2] * om - 0.5f;
        float py = ln[1] * lam + ln[3] * om - 0.5f;
        float px0 = fminf(fmaxf(floorf(px), 0.0f), 127.0f);
        float py0 = fminf(fmaxf(floorf(py), 0.0f), 127.0f);
        float px1 = fminf(px0 + 1.0f, 127.0f);
        float py1 = fminf(py0 + 1.0f, 127.0f);
        int ix0 = (int)px0, ix1 = (int)px1, iy0 = (int)py0, iy1 = (int)py1;
        s_oA[tid] = (iy0 * WW + ix0) * CC;
        s_oB[tid] = (iy1 * WW + ix0) * CC;
        s_oC[tid] = (iy0 * WW + ix1) * CC;
        s_oD[tid] = (iy1 * WW + ix1) * CC;
        float ax = px1 - px, bxv = px - px0, ay = py1 - py, byv = py - py0;
        // exact reference pairing (its bilinear weights are x/y-swapped)
        s_wA[tid] = ax  * ay;
        s_wB[tid] = bxv * ay;
        s_wC[tid] = ax  * byv;
        s_wD[tid] = bxv * byv;
    }
    __syncthreads();

    // ---- P1: bf16 gather + bilinear + maxpool(4) -> s_xs (bf16) ----
    #pragma unroll 1
    for (int h = 0; h < 2; ++h) {
        int m = h * 16 + (tid >> 4);      // 0..31 = line*8 + k
        int line = m >> 3, k = m & 7;
        int c8 = (tid & 15) * 8;
        const unsigned short* base = fmT + (size_t)b * (HH * WW * CC) + c8;
        float acc[8];
        #pragma unroll
        for (int i = 0; i < 8; ++i) acc[i] = -INFINITY;
        #pragma unroll
        for (int j = 0; j < 4; ++j) {
            int pt = line * 32 + k * 4 + j;
            bf16x8 rA = *(const bf16x8*)(base + s_oA[pt]);
            bf16x8 rB = *(const bf16x8*)(base + s_oB[pt]);
            bf16x8 rC = *(const bf16x8*)(base + s_oC[pt]);
            bf16x8 rD = *(const bf16x8*)(base + s_oD[pt]);
            float wA = s_wA[pt], wB = s_wB[pt], wC = s_wC[pt], wD = s_wD[pt];
            #pragma unroll
            for (int i = 0; i < 8; ++i) {
                float v = wA * bf2f((unsigned short)rA[i])
                        + wB * bf2f((unsigned short)rB[i])
                        + wC * bf2f((unsigned short)rC[i])
                        + wD * bf2f((unsigned short)rD[i]);
                acc[i] = fmaxf(acc[i], v);
            }
        }
        bf16x8 pk;
        #pragma unroll
        for (int i = 0; i < 8; ++i) pk[i] = (short)f2bf(acc[i]);
        *(bf16x8*)&s_xs[m * 136 + c8] = pk;
    }
    __syncthreads();   // also retires s_o*/s_w* reads before s_z1 overwrites

    // ---- P2: conv1 (M=32,K=128,N=64), bn1 applied in-register -> s_z1 ----
    {
        int mh = wv & 1, nh = wv >> 1;
        int mrow = mh * 16 + l16;
        bf16x8 afr[4];
        #pragma unroll
        for (int kc = 0; kc < 4; ++kc) {
            bf16x8 x = *(const bf16x8*)&s_xs[mrow * 136 + kc * 32 + quad * 8];
            int c0 = kc * 32 + quad * 8;
            float4 g0 = *(const float4*)(bn1_g + c0);
            float4 g1 = *(const float4*)(bn1_g + c0 + 4);
            float4 bb0 = *(const float4*)(bn1_b + c0);
            float4 bb1 = *(const float4*)(bn1_b + c0 + 4);
            float gs[8] = {g0.x, g0.y, g0.z, g0.w, g1.x, g1.y, g1.z, g1.w};
            float bs[8] = {bb0.x, bb0.y, bb0.z, bb0.w, bb1.x, bb1.y, bb1.z, bb1.w};
            bf16x8 pk;
            #pragma unroll
            for (int i = 0; i < 8; ++i) {
                float v = fmaxf(bf2f((unsigned short)x[i]) * (gs[i] * inv_s) + bs[i], 0.0f);
                pk[i] = (short)f2bf(v);
            }
            afr[kc] = pk;
        }
        #pragma unroll
        for (int sub = 0; sub < 2; ++sub) {
            int p = nh * 32 + sub * 16 + l16;
            f32x4 acc = {0.f, 0.f, 0.f, 0.f};
            #pragma unroll
            for (int kc = 0; kc < 4; ++kc) {
                bf16x8 bf = *(const bf16x8*)(W1b + p * 128 + kc * 32 + quad * 8);
                acc = __builtin_amdgcn_mfma_f32_16x16x32_bf16(afr[kc], bf, acc, 0, 0, 0);
            }
            float s2 = bn2_g[p] * inv_s, bb2 = bn2_b[p], cb = b1[p];
            #pragma unroll
            for (int r = 0; r < 4; ++r) {
                int mm = mh * 16 + quad * 4 + r;
                int lline = mm >> 3, kk = mm & 7;
                float v = fmaxf((acc[r] + cb) * s2 + bb2, 0.0f);
                s_z1[lline * 720 + (kk + 1) * 72 + p] = f2bf(v);
            }
        }
        // halo rows 0/9 of each line's z1 tile
        #pragma unroll
        for (int e = tid; e < 512; e += 256) {
            int lline = e >> 7;
            int rr = (e >> 6) & 1;
            int q = e & 63;
            s_z1[lline * 720 + (rr ? 9 : 0) * 72 + q] = 0;
        }
    }
    __syncthreads();

    // ---- P3: conv2 (3 shifted GEMMs, M=32,K=64,N=64) + bn3 + relu -> s_z2 ----
    {
        int mh = wv & 1, nh = wv >> 1;
        int mrow = mh * 16 + l16;
        int linea = mrow >> 3, ka = mrow & 7;
        const unsigned short* arow = s_z1 + linea * 720 + ka * 72;
        bf16x8 afr[3][2];
        #pragma unroll
        for (int t = 0; t < 3; ++t)
            #pragma unroll
            for (int kc = 0; kc < 2; ++kc)
                afr[t][kc] = *(const bf16x8*)&arow[t * 72 + kc * 32 + quad * 8];
        #pragma unroll
        for (int sub = 0; sub < 2; ++sub) {
            int p = nh * 32 + sub * 16 + l16;
            f32x4 acc = {0.f, 0.f, 0.f, 0.f};
            #pragma unroll
            for (int t = 0; t < 3; ++t) {
                #pragma unroll
                for (int kc = 0; kc < 2; ++kc) {
                    bf16x8 bf = *(const bf16x8*)(W2b + t * 4096 + p * 64 + kc * 32 + quad * 8);
                    acc = __builtin_amdgcn_mfma_f32_16x16x32_bf16(afr[t][kc], bf, acc, 0, 0, 0);
                }
            }
            float s3 = bn3_g[p] * inv_s, bb3 = bn3_b[p], cb = b2[p];
            #pragma unroll
            for (int r = 0; r < 4; ++r) {
                int mm = mh * 16 + quad * 4 + r;
                float v = fmaxf((acc[r] + cb) * s3 + bb3, 0.0f);
                s_z2[mm * 72 + p] = f2bf(v);
            }
        }
    }
    __syncthreads();

    // ---- P4: conv3 (M=32,K=64,N=128) + residual + relu + fc2 partials ----
    float p0 = 0.f, p1 = 0.f, p2 = 0.f, p3 = 0.f;
    {
        int mh = wv & 1;
        int n0 = (wv >> 1) * 64;
        int mrow = mh * 16 + l16;
        bf16x8 a0 = *(const bf16x8*)&s_z2[mrow * 72 + quad * 8];
        bf16x8 a1 = *(const bf16x8*)&s_z2[mrow * 72 + 32 + quad * 8];
        int kbase = (quad & 1) * 4;
        #pragma unroll
        for (int sub = 0; sub < 4; ++sub) {
            int c = n0 + sub * 16 + l16;
            f32x4 acc = {0.f, 0.f, 0.f, 0.f};
            bf16x8 bf0 = *(const bf16x8*)(W3b + c * 64 + quad * 8);
            bf16x8 bf1 = *(const bf16x8*)(W3b + c * 64 + 32 + quad * 8);
            acc = __builtin_amdgcn_mfma_f32_16x16x32_bf16(a0, bf0, acc, 0, 0, 0);
            acc = __builtin_amdgcn_mfma_f32_16x16x32_bf16(a1, bf1, acc, 0, 0, 0);
            float cb = b3[c];
            int idx = c * 8 + kbase;
            float4 w0 = *(const float4*)(fcwP + 0 * FCKP + idx);
            float4 w1v = *(const float4*)(fcwP + 1 * FCKP + idx);
            float4 w2v = *(const float4*)(fcwP + 2 * FCKP + idx);
            float4 w3v = *(const float4*)(fcwP + 3 * FCKP + idx);
            const float* w0a = (const float*)&w0;
            const float* w1a = (const float*)&w1v;
            const float* w2a = (const float*)&w2v;
            const float* w3a = (const float*)&w3v;
            #pragma unroll
            for (int r = 0; r < 4; ++r) {
                int mm = mh * 16 + quad * 4 + r;
                float xv = bf2f(s_xs[mm * 136 + c]);
                float v = fmaxf(xv + acc[r] + cb, 0.0f);
                p0 = fmaf(v, w0a[r], p0);
                p1 = fmaf(v, w1a[r], p1);
                p2 = fmaf(v, w2a[r], p2);
                p3 = fmaf(v, w3a[r], p3);
            }
        }
    }
    // reduce within 32-lane halves (each half = one line of this wave's m-half)
    #pragma unroll
    for (int off = 16; off >= 1; off >>= 1) {
        p0 += __shfl_down(p0, off);
        p1 += __shfl_down(p1, off);
        p2 += __shfl_down(p2, off);
        p3 += __shfl_down(p3, off);
    }
    if ((lane & 31) == 0) {
        int h = lane >> 5;
        s_red[wv * 8 + h * 4 + 0] = p0;
        s_red[wv * 8 + h * 4 + 1] = p1;
        s_red[wv * 8 + h * 4 + 2] = p2;
        s_red[wv * 8 + h * 4 + 3] = p3;
    }
    __syncthreads();

    // ---- P5: finish logits + softmax (one thread per line) ----
    if (tid < 4) {
        int line = tid;
        int wa = line >> 1;              // wave with matching m-half, n-half 0
        int h  = (line & 1) * 4;
        float lg[4];
        #pragma unroll
        for (int o = 0; o < 4; ++o)
            lg[o] = fcb[o] + s_red[wa * 8 + h + o] + s_red[(wa + 2) * 8 + h + o];
        const float* ln = lines + (size_t)(L0 + line) * 4;
        float ux = ln[0], uy = ln[1], vx = ln[2], vy = ln[3];
        float dx = ux - vx, dy = uy - vy;
        float d = fmaxf(sqrtf(dx * dx + dy * dy), 1e-6f);
        float ft[FDIM] = {ux * (1.0f / 128.0f), uy * (1.0f / 128.0f),
                          vx * (1.0f / 128.0f), vy * (1.0f / 128.0f), d};
        #pragma unroll
        for (int j = 0; j < FDIM; ++j) {
            float fv = fmaxf(ft[j], 0.0f);
            #pragma unroll
            for (int o = 0; o < 4; ++o)
                lg[o] = fmaf(fv, fcwP[o * FCKP + 1024 + j], lg[o]);
        }
        float m = fmaxf(fmaxf(lg[0], lg[1]), fmaxf(lg[2], lg[3]));
        float e0 = expf(lg[0] - m), e1 = expf(lg[1] - m);
        float e2 = expf(lg[2] - m), e3 = expf(lg[3] - m);
        float inv = 1.0f / (e0 + e1 + e2 + e3);
        float* lo = out + (size_t)(L0 + line) * 4;
        lo[0] = lg[0]; lo[1] = lg[1]; lo[2] = lg[2]; lo[3] = lg[3];
        float* pr = out + (size_t)BB * NLL * 4 + (size_t)(L0 + line) * 4;
        pr[0] = e0 * inv; pr[1] = e1 * inv; pr[2] = e2 * inv; pr[3] = e3 * inv;
    }
}

// ---------------------------------------------------------------------------
// Fallbacks (small-ws paths): round-1 proven VALU kernel + fp32 transpose.
// ---------------------------------------------------------------------------
__global__ __launch_bounds__(256)
void transpose_fm2(const float* __restrict__ fm, float* __restrict__ fmT) {
    __shared__ float tile[32 * 132];
    const int c0 = blockIdx.x * 32;
    const int by = blockIdx.y;
    const int b = by >> 7, y = by & 127;
    const int t = threadIdx.x;
    const float* src = fm + ((size_t)b * CC) * (HH * WW) + (size_t)y * WW;
    const int x4 = (t & 31) * 4;
    #pragma unroll
    for (int i = 0; i < 4; ++i) {
        int r = (t >> 5) + 8 * i;
        *(float4*)&tile[r * 132 + x4] =
            *(const float4*)&src[(size_t)(c0 + r) * (HH * WW) + x4];
    }
    __syncthreads();
    float* dst = fmT + (size_t)by * WW * CC + c0 + (t & 31);
    const int cr = (t & 31) * 132;
    #pragma unroll
    for (int i = 0; i < 16; ++i) {
        int x = (t >> 5) + 8 * i;
        dst[(size_t)x * CC] = tile[cr + x];
    }
}

template<bool TRANS>
__global__ __launch_bounds__(256)
void line_kernel_v1(const float* __restrict__ fm,
                    const float* __restrict__ lines,
                    const float* __restrict__ bn1_g, const float* __restrict__ bn1_b,
                    const float* __restrict__ w1,    const float* __restrict__ b1,
                    const float* __restrict__ bn2_g, const float* __restrict__ bn2_b,
                    const float* __restrict__ w2,    const float* __restrict__ b2,
                    const float* __restrict__ bn3_g, const float* __restrict__ bn3_b,
                    const float* __restrict__ w3,    const float* __restrict__ b3,
                    const float* __restrict__ fcw,   const float* __restrict__ fcb,
                    float* __restrict__ out) {
    __shared__ int   s_ix0[32], s_ix1[32], s_iy0[32], s_iy1[32];
    __shared__ float s_wA[32], s_wB[32], s_wC[32], s_wD[32];
    __shared__ float xs [8][132];
    __shared__ float ybn[8][132];
    __shared__ float z1 [64][12];
    __shared__ float z2 [64][8];
    __shared__ float s_feat[8];
    __shared__ float s_red[16];

    const int L   = blockIdx.x;
    const int b   = L / NLL;
    const int tid = threadIdx.x;
    const float inv_s = 1.0f / sqrtf(1.0f + 1e-5f);
    const float* ln = lines + (size_t)L * 4;

    if (tid < 32) {
        float lam = (float)tid * (1.0f / 31.0f);
        float om  = 1.0f - lam;
        float px = ln[0] * lam + ln[2] * om - 0.5f;
        float py = ln[1] * lam + ln[3] * om - 0.5f;
        float px0 = fminf(fmaxf(floorf(px), 0.0f), 127.0f);
        float py0 = fminf(fmaxf(floorf(py), 0.0f), 127.0f);
        float px1 = fminf(px0 + 1.0f, 127.0f);
        float py1 = fminf(py0 + 1.0f, 127.0f);
        s_ix0[tid] = (int)px0; s_ix1[tid] = (int)px1;
        s_iy0[tid] = (int)py0; s_iy1[tid] = (int)py1;
        float ax = px1 - px, bxv = px - px0, ay = py1 - py, byv = py - py0;
        s_wA[tid] = ax  * ay;  s_wB[tid] = bxv * ay;
        s_wC[tid] = ax  * byv; s_wD[tid] = bxv * byv;
    }
    if (tid == 0) {
        float ux = ln[0], uy = ln[1], vx = ln[2], vy = ln[3];
        float dx = ux - vx, dy = uy - vy;
        float d = fmaxf(sqrtf(dx * dx + dy * dy), 1e-6f);
        s_feat[0] = ux / 128.0f; s_feat[1] = uy / 128.0f;
        s_feat[2] = vx / 128.0f; s_feat[3] = vy / 128.0f;
        s_feat[4] = d;
    }
    __syncthreads();
    {
        int cq = tid & 31, k = tid >> 5, c0 = cq * 4;
        float4 acc;
        acc.x = -INFINITY; acc.y = -INFINITY; acc.z = -INFINITY; acc.w = -INFINITY;
        #pragma unroll
        for (int j = 0; j < 4; ++j) {
            int pt = k * 4 + j;
            int ix0 = s_ix0[pt], ix1 = s_ix1[pt];
            int iy0 = s_iy0[pt], iy1 = s_iy1[pt];
            float wA = s_wA[pt], wB = s_wB[pt], wC = s_wC[pt], wD = s_wD[pt];
            float4 vA, vB, vC, vD;
            if (TRANS) {
                const float* base = fm + (size_t)b * HH * WW * CC;
                vA = *(const float4*)(base + ((size_t)(iy0 * WW + ix0)) * CC + c0);
                vB = *(const float4*)(base + ((size_t)(iy1 * WW + ix0)) * CC + c0);
                vC = *(const float4*)(base + ((size_t)(iy0 * WW + ix1)) * CC + c0);
                vD = *(const float4*)(base + ((size_t)(iy1 * WW + ix1)) * CC + c0);
            } else {
                const float* base = fm + ((size_t)b * CC + c0) * HH * WW;
                int oA = iy0 * WW + ix0, oB = iy1 * WW + ix0;
                int oC = iy0 * WW + ix1, oD = iy1 * WW + ix1;
                vA.x = base[oA];           vB.x = base[oB];
                vC.x = base[oC];           vD.x = base[oD];
                vA.y = base[HH*WW + oA];   vB.y = base[HH*WW + oB];
                vC.y = base[HH*WW + oC];   vD.y = base[HH*WW + oD];
                vA.z = base[2*HH*WW + oA]; vB.z = base[2*HH*WW + oB];
                vC.z = base[2*HH*WW + oC]; vD.z = base[2*HH*WW + oD];
                vA.w = base[3*HH*WW + oA]; vB.w = base[3*HH*WW + oB];
                vC.w = base[3*HH*WW + oC]; vD.w = base[3*HH*WW + oD];
            }
            float4 v;
            v.x = wA * vA.x + wB * vB.x + wC * vC.x + wD * vD.x;
            v.y = wA * vA.y + wB * vB.y + wC * vC.y + wD * vD.y;
            v.z = wA * vA.z + wB * vB.z + wC * vC.z + wD * vD.z;
            v.w = wA * vA.w + wB * vB.w + wC * vC.w + wD * vD.w;
            acc.x = fmaxf(acc.x, v.x); acc.y = fmaxf(acc.y, v.y);
            acc.z = fmaxf(acc.z, v.z); acc.w = fmaxf(acc.w, v.w);
        }
        *(float4*)(&xs[k][c0]) = acc;
    }
    __syncthreads();
    for (int e = tid; e < 1024; e += 256) {
        int k = e >> 7, c = e & 127;
        ybn[k][c] = fmaxf(xs[k][c] * (bn1_g[c] * inv_s) + bn1_b[c], 0.0f);
    }
    __syncthreads();
    if (tid < 64) { z1[tid][0] = 0.0f; z1[tid][9] = 0.0f; }
    {
        int p = tid >> 2, kq = tid & 3;
        const float* wrow = w1 + p * 128;
        float a0a = 0.f, a0b = 0.f, a1a = 0.f, a1b = 0.f;
        #pragma unroll 8
        for (int c = 0; c < 128; c += 4) {
            float4 w  = *(const float4*)(wrow + c);
            float4 ya = *(const float4*)(&ybn[kq][c]);
            float4 yb = *(const float4*)(&ybn[kq + 4][c]);
            a0a = fmaf(w.x, ya.x, a0a); a0b = fmaf(w.y, ya.y, a0b);
            a0a = fmaf(w.z, ya.z, a0a); a0b = fmaf(w.w, ya.w, a0b);
            a1a = fmaf(w.x, yb.x, a1a); a1b = fmaf(w.y, yb.y, a1b);
            a1a = fmaf(w.z, yb.z, a1a); a1b = fmaf(w.w, yb.w, a1b);
        }
        float s2 = bn2_g[p] * inv_s, bb = bn2_b[p], cb = b1[p];
        z1[p][1 + kq]     = fmaxf((a0a + a0b + cb) * s2 + bb, 0.0f);
        z1[p][1 + kq + 4] = fmaxf((a1a + a1b + cb) * s2 + bb, 0.0f);
    }
    __syncthreads();
    {
        int p = tid >> 2, kq = tid & 3;
        const float* wrow = w2 + p * 192;
        float acc0 = 0.f, acc1 = 0.f;
        #pragma unroll 4
        for (int q = 0; q < 64; ++q) {
            float w0 = wrow[q * 3 + 0], w1v = wrow[q * 3 + 1], w2v = wrow[q * 3 + 2];
            const float* zr = &z1[q][0];
            acc0 = fmaf(w0, zr[kq], acc0);
            acc0 = fmaf(w1v, zr[kq + 1], acc0);
            acc0 = fmaf(w2v, zr[kq + 2], acc0);
            acc1 = fmaf(w0, zr[kq + 4], acc1);
            acc1 = fmaf(w1v, zr[kq + 5], acc1);
            acc1 = fmaf(w2v, zr[kq + 6], acc1);
        }
        float s3 = bn3_g[p] * inv_s, bb = bn3_b[p], cb = b2[p];
        z2[p][kq]     = fmaxf((acc0 + cb) * s3 + bb, 0.0f);
        z2[p][kq + 4] = fmaxf((acc1 + cb) * s3 + bb, 0.0f);
    }
    __syncthreads();
    float part0 = 0.f, part1 = 0.f, part2 = 0.f, part3 = 0.f;
    {
        int c = tid >> 1, kq = tid & 1;
        const float* wrow = w3 + c * 64;
        float acc[4] = {0.f, 0.f, 0.f, 0.f};
        #pragma unroll 8
        for (int q = 0; q < 64; ++q) {
            float w = wrow[q];
            acc[0] = fmaf(w, z2[q][kq], acc[0]);
            acc[1] = fmaf(w, z2[q][kq + 2], acc[1]);
            acc[2] = fmaf(w, z2[q][kq + 4], acc[2]);
            acc[3] = fmaf(w, z2[q][kq + 6], acc[3]);
        }
        float cb = b3[c];
        #pragma unroll
        for (int i = 0; i < 4; ++i) {
            int k = kq + 2 * i;
            float v = fmaxf(xs[k][c] + acc[i] + cb, 0.0f);
            int idx = c * 8 + k;
            part0 = fmaf(v, fcw[0 * FCK + idx], part0);
            part1 = fmaf(v, fcw[1 * FCK + idx], part1);
            part2 = fmaf(v, fcw[2 * FCK + idx], part2);
            part3 = fmaf(v, fcw[3 * FCK + idx], part3);
        }
    }
    #pragma unroll
    for (int off = 32; off > 0; off >>= 1) {
        part0 += __shfl_down(part0, off);
        part1 += __shfl_down(part1, off);
        part2 += __shfl_down(part2, off);
        part3 += __shfl_down(part3, off);
    }
    if ((tid & 63) == 0) {
        int w = tid >> 6;
        s_red[w * 4 + 0] = part0; s_red[w * 4 + 1] = part1;
        s_red[w * 4 + 2] = part2; s_red[w * 4 + 3] = part3;
    }
    __syncthreads();
    if (tid == 0) {
        float lg[4];
        #pragma unroll
        for (int o = 0; o < 4; ++o)
            lg[o] = fcb[o] + s_red[o] + s_red[4 + o] + s_red[8 + o] + s_red[12 + o];
        #pragma unroll
        for (int j = 0; j < FDIM; ++j) {
            float fv = fmaxf(s_feat[j], 0.0f);
            #pragma unroll
            for (int o = 0; o < 4; ++o)
                lg[o] = fmaf(fv, fcw[o * FCK + 1024 + j], lg[o]);
        }
        float m = fmaxf(fmaxf(lg[0], lg[1]), fmaxf(lg[2], lg[3]));
        float e0 = expf(lg[0] - m), e1 = expf(lg[1] - m);
        float e2 = expf(lg[2] - m), e3 = expf(lg[3] - m);
        float inv = 1.0f / (e0 + e1 + e2 + e3);
        float* lo = out + (size_t)L * 4;
        lo[0] = lg[0]; lo[1] = lg[1]; lo[2] = lg[2]; lo[3] = lg[3];
        float* pr = out + (size_t)BB * NLL * 4 + (size_t)L * 4;
        pr[0] = e0 * inv; pr[1] = e1 * inv; pr[2] = e2 * inv; pr[3] = e3 * inv;
    }
}

extern "C" void kernel_launch(void* const* d_in, const int* in_sizes, int n_in,
                              void* d_out, int out_size, void* d_ws, size_t ws_size,
                              hipStream_t stream) {
    const float* fm     = (const float*)d_in[0];
    const float* lines  = (const float*)d_in[1];
    const float* bn1_g  = (const float*)d_in[2];
    const float* bn1_b  = (const float*)d_in[3];
    const float* w1     = (const float*)d_in[4];
    const float* b1     = (const float*)d_in[5];
    const float* bn2_g  = (const float*)d_in[6];
    const float* bn2_b  = (const float*)d_in[7];
    const float* w2     = (const float*)d_in[8];
    const float* b2     = (const float*)d_in[9];
    const float* bn3_g  = (const float*)d_in[10];
    const float* bn3_b  = (const float*)d_in[11];
    const float* w3     = (const float*)d_in[12];
    const float* b3     = (const float*)d_in[13];
    const float* fcw    = (const float*)d_in[14];
    const float* fcb    = (const float*)d_in[15];
    float* out = (float*)d_out;

    const size_t fmTb_bytes = (size_t)BB * HH * WW * CC * sizeof(unsigned short); // 8 MiB
    const size_t fmTf_bytes = (size_t)BB * HH * WW * CC * sizeof(float);          // 32 MiB
    const size_t wb_bytes   = 57344;                    // W1b+W2b+W3b (bf16)
    const size_t fcwP_bytes = 4 * FCKP * sizeof(float); // 16512

    if (ws_size >= fmTb_bytes + wb_bytes + fcwP_bytes) {
        unsigned short* fmT = (unsigned short*)d_ws;
        unsigned short* W1b = (unsigned short*)((char*)d_ws + fmTb_bytes);
        unsigned short* W2b = W1b + 8192;
        unsigned short* W3b = W2b + 12288;
        float* fcwP = (float*)((char*)d_ws + fmTb_bytes + wb_bytes);
        transpose_prep<<<512 + 16, 256, 0, stream>>>(
            fm, w1, w2, w3, fcw, fmT, W1b, W2b, W3b, fcwP);
        line_mfma<<<BB * NLL / 4, 256, 0, stream>>>(
            fmT, lines, bn1_g, bn1_b, W1b, b1, bn2_g, bn2_b, W2b, b2,
            bn3_g, bn3_b, W3b, b3, fcwP, fcb, out);
    } else if (ws_size >= fmTf_bytes) {
        float* fmT = (float*)d_ws;
        dim3 tg(CC / 32, BB * HH);
        transpose_fm2<<<tg, 256, 0, stream>>>(fm, fmT);
        line_kernel_v1<true><<<BB * NLL, 256, 0, stream>>>(
            fmT, lines, bn1_g, bn1_b, w1, b1, bn2_g, bn2_b, w2, b2,
            bn3_g, bn3_b, w3, b3, fcw, fcb, out);
    } else {
        line_kernel_v1<false><<<BB * NLL, 256, 0, stream>>>(
            fm, lines, bn1_g, bn1_b, w1, b1, bn2_g, bn2_b, w2, b2,
            bn3_g, bn3_b, w3, b3, fcw, fcb, out);
    }
}

// Round 7
// 150.515 us; speedup vs baseline: 1.1769x; 1.0870x over previous
//
#include <hip/hip_runtime.h>
#include <math.h>

#define BB 4
#define NLL 2048
#define CC 128
#define HH 128
#define WW 128
#define NPTS0 32
#define NPTS1 8
#define PP 64
#define FDIM 5
#define FCK (CC*NPTS1 + FDIM)   // 1029
#define FCKP 1032               // padded stride for aligned float4 loads

typedef __attribute__((ext_vector_type(8))) short bf16x8;
typedef __attribute__((ext_vector_type(4))) float f32x4;

__device__ __forceinline__ unsigned short f2bf(float f) {
    union { float f; unsigned u; } v; v.f = f;
    unsigned u = v.u;
    return (unsigned short)((u + 0x7fffu + ((u >> 16) & 1u)) >> 16);
}
__device__ __forceinline__ float bf2f(unsigned short s) {
    union { unsigned u; float f; } v; v.u = ((unsigned)s) << 16;
    return v.f;
}

// ---------------------------------------------------------------------------
// Transpose + fused weight prep (proven round-4 version, unchanged).
// ---------------------------------------------------------------------------
__global__ __launch_bounds__(256)
void transpose_prep(const float* __restrict__ fm, const float* __restrict__ w1,
                    const float* __restrict__ w2, const float* __restrict__ w3,
                    const float* __restrict__ fcw,
                    unsigned short* __restrict__ fmT,
                    unsigned short* __restrict__ W1b,
                    unsigned short* __restrict__ W2b,
                    unsigned short* __restrict__ W3b,
                    float* __restrict__ fcwP) {
    const int t = threadIdx.x;
    if (blockIdx.x >= 512) {
        int gid = (blockIdx.x - 512) * 256 + t;
        for (int e = gid; e < 32800; e += 4096) {
            if (e < 8192) {
                W1b[e] = f2bf(w1[e]);
            } else if (e < 20480) {
                int g = e - 8192;
                int tt = g >> 12, r = g & 4095;
                int p = r >> 6, q = r & 63;
                W2b[tt * 4096 + p * 64 + q] = f2bf(w2[p * 192 + q * 3 + tt]);
            } else if (e < 28672) {
                int g = e - 20480;
                W3b[g] = f2bf(w3[g]);
            } else {
                int g = e - 28672;              // 0..4127
                int o = g / FCKP, r = g - o * FCKP;
                fcwP[g] = (r < FCK) ? fcw[o * FCK + r] : 0.0f;
            }
        }
        return;
    }
    __shared__ unsigned short tile[2][128 * 72];
    const int by = blockIdx.x;            // b*H + y
    const int b = by >> 7, y = by & 127;
    const float* src = fm + ((size_t)b * CC) * (HH * WW) + (size_t)y * WW;
    const int x4 = (t & 31) * 4;          // 0..124
    const int xh = x4 >> 6, xl = x4 & 63;
    #pragma unroll
    for (int i = 0; i < 16; ++i) {
        int r = (t >> 5) + 8 * i;         // channel 0..127
        float4 v = *(const float4*)&src[(size_t)r * (HH * WW) + x4];
        ushort4 u;
        u.x = f2bf(v.x); u.y = f2bf(v.y); u.z = f2bf(v.z); u.w = f2bf(v.w);
        *(ushort4*)&tile[xh][r * 72 + (xl ^ (r & 28))] = u;
    }
    __syncthreads();
    const int c4 = (t & 31) * 4;
    #pragma unroll
    for (int h = 0; h < 2; ++h) {
        unsigned short* dst = fmT + ((size_t)by * WW + h * 64) * CC;
        #pragma unroll
        for (int i = 0; i < 8; ++i) {
            int x = (t >> 5) + 8 * i;     // 0..63
            ushort4 u;
            u.x = tile[h][(c4 + 0) * 72 + (x ^ ((c4 + 0) & 28))];
            u.y = tile[h][(c4 + 1) * 72 + (x ^ ((c4 + 1) & 28))];
            u.z = tile[h][(c4 + 2) * 72 + (x ^ ((c4 + 2) & 28))];
            u.w = tile[h][(c4 + 3) * 72 + (x ^ ((c4 + 3) & 28))];
            *(ushort4*)&dst[(size_t)x * CC + c4] = u;
        }
    }
}

// ---------------------------------------------------------------------------
// Fused line pipeline v7 = round-4 structure (2 lines/block, proven 53 µs)
// with P1 gather loads HOISTED (16 loads in flight) and launch_bounds(256,4)
// for VGPR headroom. Tests the latency-chain hypothesis.
// MFMA 16x16x32 bf16 mapping: A[m=lane&15][k=quad*8+j], C/D col=lane&15,
// row=quad*4+reg.
// ---------------------------------------------------------------------------
__global__ __launch_bounds__(256, 4)
void line_mfma(const unsigned short* __restrict__ fmT,   // (B,H,W,C) bf16
               const float* __restrict__ lines,
               const float* __restrict__ bn1_g, const float* __restrict__ bn1_b,
               const unsigned short* __restrict__ W1b, const float* __restrict__ b1,
               const float* __restrict__ bn2_g, const float* __restrict__ bn2_b,
               const unsigned short* __restrict__ W2b, const float* __restrict__ b2,
               const float* __restrict__ bn3_g, const float* __restrict__ bn3_b,
               const unsigned short* __restrict__ W3b, const float* __restrict__ b3,
               const float* __restrict__ fcwP,  const float* __restrict__ fcb,
               float* __restrict__ out) {
    __shared__ int   s_oA[64], s_oB[64], s_oC[64], s_oD[64];   // element offsets
    __shared__ float s_wA[64], s_wB[64], s_wC[64], s_wD[64];
    __shared__ float s_xs[16 * 132];             // residual, fp32, [m][c] pad 4
    __shared__ unsigned short s_ybn[16 * 136];   // relu(bn1), bf16, [m][c]
    __shared__ unsigned short s_z1[2 * 10 * 72]; // conv1 out, halo rows 0/9 zero
    __shared__ unsigned short s_z2[16 * 72];     // conv2 out, [m][q]
    __shared__ float s_feat[2][8];
    __shared__ float s_red[4 * 8];

    const int bx  = blockIdx.x;
    const int L0  = bx * 2;
    const int b   = bx >> 10;
    const int tid = threadIdx.x;
    const int lane = tid & 63;
    const int wv   = tid >> 6;
    const int quad = lane >> 4;
    const int l16  = lane & 15;
    const float inv_s = 1.0f / sqrtf(1.0f + 1e-5f);

    // ---- P0: per-point offsets/weights, line features, halo zeroing ----
    if (tid < 64) {
        int line = tid >> 5, pt = tid & 31;
        const float* ln = lines + (size_t)(L0 + line) * 4;
        float lam = (float)pt * (1.0f / 31.0f);
        float om  = 1.0f - lam;
        float px = ln[0] * lam + ln[2] * om - 0.5f;
        float py = ln[1] * lam + ln[3] * om - 0.5f;
        float px0 = fminf(fmaxf(floorf(px), 0.0f), 127.0f);
        float py0 = fminf(fmaxf(floorf(py), 0.0f), 127.0f);
        float px1 = fminf(px0 + 1.0f, 127.0f);
        float py1 = fminf(py0 + 1.0f, 127.0f);
        int ix0 = (int)px0, ix1 = (int)px1, iy0 = (int)py0, iy1 = (int)py1;
        s_oA[tid] = (iy0 * WW + ix0) * CC;
        s_oB[tid] = (iy1 * WW + ix0) * CC;
        s_oC[tid] = (iy0 * WW + ix1) * CC;
        s_oD[tid] = (iy1 * WW + ix1) * CC;
        float ax = px1 - px, bxv = px - px0, ay = py1 - py, byv = py - py0;
        // exact reference pairing (its bilinear weights are x/y-swapped)
        s_wA[tid] = ax  * ay;
        s_wB[tid] = bxv * ay;
        s_wC[tid] = ax  * byv;
        s_wD[tid] = bxv * byv;
    }
    if (tid >= 64 && tid < 66) {
        int line = tid - 64;
        const float* ln = lines + (size_t)(L0 + line) * 4;
        float ux = ln[0], uy = ln[1], vx = ln[2], vy = ln[3];
        float dx = ux - vx, dy = uy - vy;
        float d = fmaxf(sqrtf(dx * dx + dy * dy), 1e-6f);
        s_feat[line][0] = ux * (1.0f / 128.0f);
        s_feat[line][1] = uy * (1.0f / 128.0f);
        s_feat[line][2] = vx * (1.0f / 128.0f);
        s_feat[line][3] = vy * (1.0f / 128.0f);
        s_feat[line][4] = d;
    }
    if (tid < 128) {
        int line = tid >> 6, q = tid & 63;
        s_z1[line * 720 + 0 * 72 + q] = 0;
        s_z1[line * 720 + 9 * 72 + q] = 0;
    }
    __syncthreads();

    // ---- P1: bf16 gather (ALL 16 loads hoisted) + bilinear + maxpool(4)
    //          -> s_xs (fp32) + fused bn1+relu+cvt -> s_ybn ----
    {
        int tl = tid >> 4;               // m = line*8 + k, 0..15
        int line = tl >> 3, k = tl & 7;
        int c8 = (tid & 15) * 8;
        const unsigned short* base = fmT + (size_t)b * (HH * WW * CC) + c8;
        const int pts = line * 32 + k * 4;
        bf16x8 rA[4], rB[4], rC[4], rD[4];
        // issue all 16 independent loads before any math
        #pragma unroll
        for (int j = 0; j < 4; ++j) {
            rA[j] = *(const bf16x8*)(base + s_oA[pts + j]);
            rB[j] = *(const bf16x8*)(base + s_oB[pts + j]);
            rC[j] = *(const bf16x8*)(base + s_oC[pts + j]);
            rD[j] = *(const bf16x8*)(base + s_oD[pts + j]);
        }
        float acc[8];
        #pragma unroll
        for (int i = 0; i < 8; ++i) acc[i] = -INFINITY;
        #pragma unroll
        for (int j = 0; j < 4; ++j) {
            float wA = s_wA[pts + j], wB = s_wB[pts + j];
            float wC = s_wC[pts + j], wD = s_wD[pts + j];
            #pragma unroll
            for (int i = 0; i < 8; ++i) {
                float v = wA * bf2f((unsigned short)rA[j][i])
                        + wB * bf2f((unsigned short)rB[j][i])
                        + wC * bf2f((unsigned short)rC[j][i])
                        + wD * bf2f((unsigned short)rD[j][i]);
                acc[i] = fmaxf(acc[i], v);
            }
        }
        float* xr = &s_xs[tl * 132 + c8];
        f32x4 lo = {acc[0], acc[1], acc[2], acc[3]};
        f32x4 hi = {acc[4], acc[5], acc[6], acc[7]};
        *(f32x4*)&xr[0] = lo;
        *(f32x4*)&xr[4] = hi;
        // fused bn1 + relu + cvt
        bf16x8 pack;
        #pragma unroll
        for (int i = 0; i < 8; ++i) {
            float v = fmaxf(acc[i] * (bn1_g[c8 + i] * inv_s) + bn1_b[c8 + i], 0.0f);
            pack[i] = (short)f2bf(v);
        }
        *(bf16x8*)&s_ybn[tl * 136 + c8] = pack;
    }
    __syncthreads();

    // ---- P2: conv1 (M=16,K=128,N=64) + bn2 + relu -> s_z1 ----
    {
        int n0 = wv * 16;
        f32x4 acc = {0.f, 0.f, 0.f, 0.f};
        #pragma unroll
        for (int kc = 0; kc < 4; ++kc) {
            bf16x8 a = *(const bf16x8*)&s_ybn[l16 * 136 + kc * 32 + quad * 8];
            bf16x8 bf = *(const bf16x8*)(W1b + (n0 + l16) * 128 + kc * 32 + quad * 8);
            acc = __builtin_amdgcn_mfma_f32_16x16x32_bf16(a, bf, acc, 0, 0, 0);
        }
        int p = n0 + l16;
        float s2 = bn2_g[p] * inv_s, bb2 = bn2_b[p], cb = b1[p];
        int line = quad >> 1;
        int kbase = (quad & 1) * 4;
        #pragma unroll
        for (int r = 0; r < 4; ++r) {
            float v = fmaxf((acc[r] + cb) * s2 + bb2, 0.0f);
            s_z1[line * 720 + (kbase + r + 1) * 72 + p] = f2bf(v);
        }
    }
    __syncthreads();

    // ---- P3: conv2 (3 shifted GEMMs, M=16,K=64,N=64) + bn3 + relu -> s_z2 ----
    {
        int n0 = wv * 16;
        f32x4 acc = {0.f, 0.f, 0.f, 0.f};
        int line = l16 >> 3, k = l16 & 7;
        #pragma unroll
        for (int t = 0; t < 3; ++t) {
            const unsigned short* arow = &s_z1[line * 720 + (k + t) * 72];
            #pragma unroll
            for (int kc = 0; kc < 2; ++kc) {
                bf16x8 a = *(const bf16x8*)&arow[kc * 32 + quad * 8];
                bf16x8 bf = *(const bf16x8*)(W2b + t * 4096 + (n0 + l16) * 64 + kc * 32 + quad * 8);
                acc = __builtin_amdgcn_mfma_f32_16x16x32_bf16(a, bf, acc, 0, 0, 0);
            }
        }
        int p = n0 + l16;
        float s3 = bn3_g[p] * inv_s, bb3 = bn3_b[p], cb = b2[p];
        #pragma unroll
        for (int r = 0; r < 4; ++r) {
            float v = fmaxf((acc[r] + cb) * s3 + bb3, 0.0f);
            s_z2[(quad * 4 + r) * 72 + p] = f2bf(v);
        }
    }
    __syncthreads();

    // ---- P4: conv3 (M=16,K=64,N=128) + residual + relu + fc2 partials ----
    float p0 = 0.f, p1 = 0.f, p2 = 0.f, p3 = 0.f;
    {
        int kbase = (quad & 1) * 4;
        bf16x8 a0 = *(const bf16x8*)&s_z2[l16 * 72 + 0 * 32 + quad * 8];
        bf16x8 a1 = *(const bf16x8*)&s_z2[l16 * 72 + 1 * 32 + quad * 8];
        #pragma unroll
        for (int sub = 0; sub < 2; ++sub) {
            int n0 = wv * 32 + sub * 16;
            f32x4 acc = {0.f, 0.f, 0.f, 0.f};
            bf16x8 bf0 = *(const bf16x8*)(W3b + (n0 + l16) * 64 + 0 * 32 + quad * 8);
            bf16x8 bf1 = *(const bf16x8*)(W3b + (n0 + l16) * 64 + 1 * 32 + quad * 8);
            acc = __builtin_amdgcn_mfma_f32_16x16x32_bf16(a0, bf0, acc, 0, 0, 0);
            acc = __builtin_amdgcn_mfma_f32_16x16x32_bf16(a1, bf1, acc, 0, 0, 0);
            int c = n0 + l16;
            float cb = b3[c];
            int idx = c * 8 + kbase;
            float4 w0 = *(const float4*)(fcwP + 0 * FCKP + idx);
            float4 w1v = *(const float4*)(fcwP + 1 * FCKP + idx);
            float4 w2v = *(const float4*)(fcwP + 2 * FCKP + idx);
            float4 w3v = *(const float4*)(fcwP + 3 * FCKP + idx);
            const float* w0a = (const float*)&w0;
            const float* w1a = (const float*)&w1v;
            const float* w2a = (const float*)&w2v;
            const float* w3a = (const float*)&w3v;
            #pragma unroll
            for (int r = 0; r < 4; ++r) {
                int m = quad * 4 + r;
                float v = fmaxf(s_xs[m * 132 + c] + acc[r] + cb, 0.0f);
                p0 = fmaf(v, w0a[r], p0);
                p1 = fmaf(v, w1a[r], p1);
                p2 = fmaf(v, w2a[r], p2);
                p3 = fmaf(v, w3a[r], p3);
            }
        }
    }
    #pragma unroll
    for (int off = 16; off >= 1; off >>= 1) {
        p0 += __shfl_down(p0, off);
        p1 += __shfl_down(p1, off);
        p2 += __shfl_down(p2, off);
        p3 += __shfl_down(p3, off);
    }
    if ((lane & 31) == 0) {
        int line = lane >> 5;
        s_red[wv * 8 + line * 4 + 0] = p0;
        s_red[wv * 8 + line * 4 + 1] = p1;
        s_red[wv * 8 + line * 4 + 2] = p2;
        s_red[wv * 8 + line * 4 + 3] = p3;
    }
    __syncthreads();

    // ---- P5: finish logits + softmax ----
    if (tid < 2) {
        int line = tid;
        float lg[4];
        #pragma unroll
        for (int o = 0; o < 4; ++o) {
            lg[o] = fcb[o] + s_red[0 + line * 4 + o] + s_red[8 + line * 4 + o]
                  + s_red[16 + line * 4 + o] + s_red[24 + line * 4 + o];
        }
        #pragma unroll
        for (int j = 0; j < FDIM; ++j) {
            float fv = fmaxf(s_feat[line][j], 0.0f);
            #pragma unroll
            for (int o = 0; o < 4; ++o)
                lg[o] = fmaf(fv, fcwP[o * FCKP + 1024 + j], lg[o]);
        }
        float m = fmaxf(fmaxf(lg[0], lg[1]), fmaxf(lg[2], lg[3]));
        float e0 = expf(lg[0] - m), e1 = expf(lg[1] - m);
        float e2 = expf(lg[2] - m), e3 = expf(lg[3] - m);
        float inv = 1.0f / (e0 + e1 + e2 + e3);
        float* lo = out + (size_t)(L0 + line) * 4;
        lo[0] = lg[0]; lo[1] = lg[1]; lo[2] = lg[2]; lo[3] = lg[3];
        float* pr = out + (size_t)BB * NLL * 4 + (size_t)(L0 + line) * 4;
        pr[0] = e0 * inv; pr[1] = e1 * inv; pr[2] = e2 * inv; pr[3] = e3 * inv;
    }
}

// ---------------------------------------------------------------------------
// Fallbacks (small-ws paths): round-1 proven VALU kernel + fp32 transpose.
// ---------------------------------------------------------------------------
__global__ __launch_bounds__(256)
void transpose_fm2(const float* __restrict__ fm, float* __restrict__ fmT) {
    __shared__ float tile[32 * 132];
    const int c0 = blockIdx.x * 32;
    const int by = blockIdx.y;
    const int b = by >> 7, y = by & 127;
    const int t = threadIdx.x;
    const float* src = fm + ((size_t)b * CC) * (HH * WW) + (size_t)y * WW;
    const int x4 = (t & 31) * 4;
    #pragma unroll
    for (int i = 0; i < 4; ++i) {
        int r = (t >> 5) + 8 * i;
        *(float4*)&tile[r * 132 + x4] =
            *(const float4*)&src[(size_t)(c0 + r) * (HH * WW) + x4];
    }
    __syncthreads();
    float* dst = fmT + (size_t)by * WW * CC + c0 + (t & 31);
    const int cr = (t & 31) * 132;
    #pragma unroll
    for (int i = 0; i < 16; ++i) {
        int x = (t >> 5) + 8 * i;
        dst[(size_t)x * CC] = tile[cr + x];
    }
}

template<bool TRANS>
__global__ __launch_bounds__(256)
void line_kernel_v1(const float* __restrict__ fm,
                    const float* __restrict__ lines,
                    const float* __restrict__ bn1_g, const float* __restrict__ bn1_b,
                    const float* __restrict__ w1,    const float* __restrict__ b1,
                    const float* __restrict__ bn2_g, const float* __restrict__ bn2_b,
                    const float* __restrict__ w2,    const float* __restrict__ b2,
                    const float* __restrict__ bn3_g, const float* __restrict__ bn3_b,
                    const float* __restrict__ w3,    const float* __restrict__ b3,
                    const float* __restrict__ fcw,   const float* __restrict__ fcb,
                    float* __restrict__ out) {
    __shared__ int   s_ix0[32], s_ix1[32], s_iy0[32], s_iy1[32];
    __shared__ float s_wA[32], s_wB[32], s_wC[32], s_wD[32];
    __shared__ float xs [8][132];
    __shared__ float ybn[8][132];
    __shared__ float z1 [64][12];
    __shared__ float z2 [64][8];
    __shared__ float s_feat[8];
    __shared__ float s_red[16];

    const int L   = blockIdx.x;
    const int b   = L / NLL;
    const int tid = threadIdx.x;
    const float inv_s = 1.0f / sqrtf(1.0f + 1e-5f);
    const float* ln = lines + (size_t)L * 4;

    if (tid < 32) {
        float lam = (float)tid * (1.0f / 31.0f);
        float om  = 1.0f - lam;
        float px = ln[0] * lam + ln[2] * om - 0.5f;
        float py = ln[1] * lam + ln[3] * om - 0.5f;
        float px0 = fminf(fmaxf(floorf(px), 0.0f), 127.0f);
        float py0 = fminf(fmaxf(floorf(py), 0.0f), 127.0f);
        float px1 = fminf(px0 + 1.0f, 127.0f);
        float py1 = fminf(py0 + 1.0f, 127.0f);
        s_ix0[tid] = (int)px0; s_ix1[tid] = (int)px1;
        s_iy0[tid] = (int)py0; s_iy1[tid] = (int)py1;
        float ax = px1 - px, bxv = px - px0, ay = py1 - py, byv = py - py0;
        s_wA[tid] = ax  * ay;  s_wB[tid] = bxv * ay;
        s_wC[tid] = ax  * byv; s_wD[tid] = bxv * byv;
    }
    if (tid == 0) {
        float ux = ln[0], uy = ln[1], vx = ln[2], vy = ln[3];
        float dx = ux - vx, dy = uy - vy;
        float d = fmaxf(sqrtf(dx * dx + dy * dy), 1e-6f);
        s_feat[0] = ux / 128.0f; s_feat[1] = uy / 128.0f;
        s_feat[2] = vx / 128.0f; s_feat[3] = vy / 128.0f;
        s_feat[4] = d;
    }
    __syncthreads();
    {
        int cq = tid & 31, k = tid >> 5, c0 = cq * 4;
        float4 acc;
        acc.x = -INFINITY; acc.y = -INFINITY; acc.z = -INFINITY; acc.w = -INFINITY;
        #pragma unroll
        for (int j = 0; j < 4; ++j) {
            int pt = k * 4 + j;
            int ix0 = s_ix0[pt], ix1 = s_ix1[pt];
            int iy0 = s_iy0[pt], iy1 = s_iy1[pt];
            float wA = s_wA[pt], wB = s_wB[pt], wC = s_wC[pt], wD = s_wD[pt];
            float4 vA, vB, vC, vD;
            if (TRANS) {
                const float* base = fm + (size_t)b * HH * WW * CC;
                vA = *(const float4*)(base + ((size_t)(iy0 * WW + ix0)) * CC + c0);
                vB = *(const float4*)(base + ((size_t)(iy1 * WW + ix0)) * CC + c0);
                vC = *(const float4*)(base + ((size_t)(iy0 * WW + ix1)) * CC + c0);
                vD = *(const float4*)(base + ((size_t)(iy1 * WW + ix1)) * CC + c0);
            } else {
                const float* base = fm + ((size_t)b * CC + c0) * HH * WW;
                int oA = iy0 * WW + ix0, oB = iy1 * WW + ix0;
                int oC = iy0 * WW + ix1, oD = iy1 * WW + ix1;
                vA.x = base[oA];           vB.x = base[oB];
                vC.x = base[oC];           vD.x = base[oD];
                vA.y = base[HH*WW + oA];   vB.y = base[HH*WW + oB];
                vC.y = base[HH*WW + oC];   vD.y = base[HH*WW + oD];
                vA.z = base[2*HH*WW + oA]; vB.z = base[2*HH*WW + oB];
                vC.z = base[2*HH*WW + oC]; vD.z = base[2*HH*WW + oD];
                vA.w = base[3*HH*WW + oA]; vB.w = base[3*HH*WW + oB];
                vC.w = base[3*HH*WW + oC]; vD.w = base[3*HH*WW + oD];
            }
            float4 v;
            v.x = wA * vA.x + wB * vB.x + wC * vC.x + wD * vD.x;
            v.y = wA * vA.y + wB * vB.y + wC * vC.y + wD * vD.y;
            v.z = wA * vA.z + wB * vB.z + wC * vC.z + wD * vD.z;
            v.w = wA * vA.w + wB * vB.w + wC * vC.w + wD * vD.w;
            acc.x = fmaxf(acc.x, v.x); acc.y = fmaxf(acc.y, v.y);
            acc.z = fmaxf(acc.z, v.z); acc.w = fmaxf(acc.w, v.w);
        }
        *(float4*)(&xs[k][c0]) = acc;
    }
    __syncthreads();
    for (int e = tid; e < 1024; e += 256) {
        int k = e >> 7, c = e & 127;
        ybn[k][c] = fmaxf(xs[k][c] * (bn1_g[c] * inv_s) + bn1_b[c], 0.0f);
    }
    __syncthreads();
    if (tid < 64) { z1[tid][0] = 0.0f; z1[tid][9] = 0.0f; }
    {
        int p = tid >> 2, kq = tid & 3;
        const float* wrow = w1 + p * 128;
        float a0a = 0.f, a0b = 0.f, a1a = 0.f, a1b = 0.f;
        #pragma unroll 8
        for (int c = 0; c < 128; c += 4) {
            float4 w  = *(const float4*)(wrow + c);
            float4 ya = *(const float4*)(&ybn[kq][c]);
            float4 yb = *(const float4*)(&ybn[kq + 4][c]);
            a0a = fmaf(w.x, ya.x, a0a); a0b = fmaf(w.y, ya.y, a0b);
            a0a = fmaf(w.z, ya.z, a0a); a0b = fmaf(w.w, ya.w, a0b);
            a1a = fmaf(w.x, yb.x, a1a); a1b = fmaf(w.y, yb.y, a1b);
            a1a = fmaf(w.z, yb.z, a1a); a1b = fmaf(w.w, yb.w, a1b);
        }
        float s2 = bn2_g[p] * inv_s, bb = bn2_b[p], cb = b1[p];
        z1[p][1 + kq]     = fmaxf((a0a + a0b + cb) * s2 + bb, 0.0f);
        z1[p][1 + kq + 4] = fmaxf((a1a + a1b + cb) * s2 + bb, 0.0f);
    }
    __syncthreads();
    {
        int p = tid >> 2, kq = tid & 3;
        const float* wrow = w2 + p * 192;
        float acc0 = 0.f, acc1 = 0.f;
        #pragma unroll 4
        for (int q = 0; q < 64; ++q) {
            float w0 = wrow[q * 3 + 0], w1v = wrow[q * 3 + 1], w2v = wrow[q * 3 + 2];
            const float* zr = &z1[q][0];
            acc0 = fmaf(w0, zr[kq], acc0);
            acc0 = fmaf(w1v, zr[kq + 1], acc0);
            acc0 = fmaf(w2v, zr[kq + 2], acc0);
            acc1 = fmaf(w0, zr[kq + 4], acc1);
            acc1 = fmaf(w1v, zr[kq + 5], acc1);
            acc1 = fmaf(w2v, zr[kq + 6], acc1);
        }
        float s3 = bn3_g[p] * inv_s, bb = bn3_b[p], cb = b2[p];
        z2[p][kq]     = fmaxf((acc0 + cb) * s3 + bb, 0.0f);
        z2[p][kq + 4] = fmaxf((acc1 + cb) * s3 + bb, 0.0f);
    }
    __syncthreads();
    float part0 = 0.f, part1 = 0.f, part2 = 0.f, part3 = 0.f;
    {
        int c = tid >> 1, kq = tid & 1;
        const float* wrow = w3 + c * 64;
        float acc[4] = {0.f, 0.f, 0.f, 0.f};
        #pragma unroll 8
        for (int q = 0; q < 64; ++q) {
            float w = wrow[q];
            acc[0] = fmaf(w, z2[q][kq], acc[0]);
            acc[1] = fmaf(w, z2[q][kq + 2], acc[1]);
            acc[2] = fmaf(w, z2[q][kq + 4], acc[2]);
            acc[3] = fmaf(w, z2[q][kq + 6], acc[3]);
        }
        float cb = b3[c];
        #pragma unroll
        for (int i = 0; i < 4; ++i) {
            int k = kq + 2 * i;
            float v = fmaxf(xs[k][c] + acc[i] + cb, 0.0f);
            int idx = c * 8 + k;
            part0 = fmaf(v, fcw[0 * FCK + idx], part0);
            part1 = fmaf(v, fcw[1 * FCK + idx], part1);
            part2 = fmaf(v, fcw[2 * FCK + idx], part2);
            part3 = fmaf(v, fcw[3 * FCK + idx], part3);
        }
    }
    #pragma unroll
    for (int off = 32; off > 0; off >>= 1) {
        part0 += __shfl_down(part0, off);
        part1 += __shfl_down(part1, off);
        part2 += __shfl_down(part2, off);
        part3 += __shfl_down(part3, off);
    }
    if ((tid & 63) == 0) {
        int w = tid >> 6;
        s_red[w * 4 + 0] = part0; s_red[w * 4 + 1] = part1;
        s_red[w * 4 + 2] = part2; s_red[w * 4 + 3] = part3;
    }
    __syncthreads();
    if (tid == 0) {
        float lg[4];
        #pragma unroll
        for (int o = 0; o < 4; ++o)
            lg[o] = fcb[o] + s_red[o] + s_red[4 + o] + s_red[8 + o] + s_red[12 + o];
        #pragma unroll
        for (int j = 0; j < FDIM; ++j) {
            float fv = fmaxf(s_feat[j], 0.0f);
            #pragma unroll
            for (int o = 0; o < 4; ++o)
                lg[o] = fmaf(fv, fcw[o * FCK + 1024 + j], lg[o]);
        }
        float m = fmaxf(fmaxf(lg[0], lg[1]), fmaxf(lg[2], lg[3]));
        float e0 = expf(lg[0] - m), e1 = expf(lg[1] - m);
        float e2 = expf(lg[2] - m), e3 = expf(lg[3] - m);
        float inv = 1.0f / (e0 + e1 + e2 + e3);
        float* lo = out + (size_t)L * 4;
        lo[0] = lg[0]; lo[1] = lg[1]; lo[2] = lg[2]; lo[3] = lg[3];
        float* pr = out + (size_t)BB * NLL * 4 + (size_t)L * 4;
        pr[0] = e0 * inv; pr[1] = e1 * inv; pr[2] = e2 * inv; pr[3] = e3 * inv;
    }
}

extern "C" void kernel_launch(void* const* d_in, const int* in_sizes, int n_in,
                              void* d_out, int out_size, void* d_ws, size_t ws_size,
                              hipStream_t stream) {
    const float* fm     = (const float*)d_in[0];
    const float* lines  = (const float*)d_in[1];
    const float* bn1_g  = (const float*)d_in[2];
    const float* bn1_b  = (const float*)d_in[3];
    const float* w1     = (const float*)d_in[4];
    const float* b1     = (const float*)d_in[5];
    const float* bn2_g  = (const float*)d_in[6];
    const float* bn2_b  = (const float*)d_in[7];
    const float* w2     = (const float*)d_in[8];
    const float* b2     = (const float*)d_in[9];
    const float* bn3_g  = (const float*)d_in[10];
    const float* bn3_b  = (const float*)d_in[11];
    const float* w3     = (const float*)d_in[12];
    const float* b3     = (const float*)d_in[13];
    const float* fcw    = (const float*)d_in[14];
    const float* fcb    = (const float*)d_in[15];
    float* out = (float*)d_out;

    const size_t fmTb_bytes = (size_t)BB * HH * WW * CC * sizeof(unsigned short); // 8 MiB
    const size_t fmTf_bytes = (size_t)BB * HH * WW * CC * sizeof(float);          // 32 MiB
    const size_t wb_bytes   = 57344;                    // W1b+W2b+W3b (bf16)
    const size_t fcwP_bytes = 4 * FCKP * sizeof(float); // 16512

    if (ws_size >= fmTb_bytes + wb_bytes + fcwP_bytes) {
        unsigned short* fmT = (unsigned short*)d_ws;
        unsigned short* W1b = (unsigned short*)((char*)d_ws + fmTb_bytes);
        unsigned short* W2b = W1b + 8192;
        unsigned short* W3b = W2b + 12288;
        float* fcwP = (float*)((char*)d_ws + fmTb_bytes + wb_bytes);
        transpose_prep<<<512 + 16, 256, 0, stream>>>(
            fm, w1, w2, w3, fcw, fmT, W1b, W2b, W3b, fcwP);
        line_mfma<<<BB * NLL / 2, 256, 0, stream>>>(
            fmT, lines, bn1_g, bn1_b, W1b, b1, bn2_g, bn2_b, W2b, b2,
            bn3_g, bn3_b, W3b, b3, fcwP, fcb, out);
    } else if (ws_size >= fmTf_bytes) {
        float* fmT = (float*)d_ws;
        dim3 tg(CC / 32, BB * HH);
        transpose_fm2<<<tg, 256, 0, stream>>>(fm, fmT);
        line_kernel_v1<true><<<BB * NLL, 256, 0, stream>>>(
            fmT, lines, bn1_g, bn1_b, w1, b1, bn2_g, bn2_b, w2, b2,
            bn3_g, bn3_b, w3, b3, fcw, fcb, out);
    } else {
        line_kernel_v1<false><<<BB * NLL, 256, 0, stream>>>(
            fm, lines, bn1_g, bn1_b, w1, b1, bn2_g, bn2_b, w2, b2,
            bn3_g, bn3_b, w3, b3, fcw, fcb, out);
    }
}